// Round 17
// baseline (1767.112 us; speedup 1.0000x reference)
//
#include <hip/hip_runtime.h>
#include <hip/hip_bf16.h>

typedef _Float16 f16;
typedef _Float16 f16x8 __attribute__((ext_vector_type(8)));
typedef float f32x4 __attribute__((ext_vector_type(4)));

#define NTOK 16384   // 16*64*16 tokens
#define EDIM 512
#define FFDIM 2048
#define PDIM 768

#define VMCNT(n) asm volatile("s_waitcnt vmcnt(" #n ")")

// async global->LDS DMA, 16B per lane. LDS dest must be linear in lane order.
typedef __attribute__((address_space(3))) unsigned int lds_uint;
typedef __attribute__((address_space(1))) const unsigned int glob_uint;
__device__ __forceinline__ void gl_lds16(const f16* g, f16* l) {
  __builtin_amdgcn_global_load_lds((glob_uint*)g, (lds_uint*)l, 16, 0, 0);
}

// ======== weight transpose: fp32 [B][R][C] -> fp16 [B][C][R] ========
__global__ void k_transpose(const float* __restrict__ src, f16* __restrict__ dst,
                            int R, int C, long srcBS, long dstBS) {
  __shared__ float tile[32][33];
  src += (long)blockIdx.z * srcBS;
  dst += (long)blockIdx.z * dstBS;
  int c0 = blockIdx.x * 32, r0 = blockIdx.y * 32;
  int tx = threadIdx.x, ty = threadIdx.y;
#pragma unroll
  for (int j = ty; j < 32; j += 8)
    tile[j][tx] = src[(long)(r0 + j) * C + (c0 + tx)];
  __syncthreads();
#pragma unroll
  for (int j = ty; j < 32; j += 8)
    dst[(long)(c0 + j) * R + (r0 + tx)] = (f16)tile[tx][j];
}

// ======== pack QKV biases -> [2][6][1536] fp32 ========
__global__ void k_pack_bias(const float* __restrict__ sq, const float* __restrict__ sk,
                            const float* __restrict__ sv, const float* __restrict__ tq,
                            const float* __restrict__ tk, const float* __restrict__ tv,
                            float* __restrict__ dst) {
  int i = blockIdx.x * 256 + threadIdx.x;
  if (i >= 2 * 6 * 1536) return;
  int pre = i / (6 * 1536), rem = i % (6 * 1536), l = rem / 1536, e = rem % 1536;
  const float* s;
  if (pre == 0) s = (e < 512) ? sq : (e < 1024) ? sk : sv;
  else          s = (e < 512) ? tq : (e < 1024) ? tk : tv;
  dst[i] = s[l * 512 + (e & 511)];
}

// ======== patchify: frames fp32 [16][64][3][64][64] -> P fp16 [16384][768] ========
__global__ void k_patchify(const float* __restrict__ frames, f16* __restrict__ P) {
  int gid = blockIdx.x * 256 + threadIdx.x;           // < 16384*96
  int token = gid / 96, chunk = gid % 96;
  int b = token >> 10, s = (token >> 4) & 63, p = token & 15;
  int c = chunk >> 5, rem = chunk & 31, p1 = rem >> 1, p2b = (rem & 1) * 8;
  int h = p >> 2, w = p & 3;
  const float* src = frames + ((long)(((b * 64 + s) * 3 + c) * 64 + h * 16 + p1)) * 64 + w * 16 + p2b;
  float4 f0 = *reinterpret_cast<const float4*>(src);
  float4 f1 = *reinterpret_cast<const float4*>(src + 4);
  f16* dst = P + (long)token * PDIM + chunk * 8;
  dst[0] = (f16)f0.x; dst[1] = (f16)f0.y; dst[2] = (f16)f0.z; dst[3] = (f16)f0.w;
  dst[4] = (f16)f1.x; dst[5] = (f16)f1.y; dst[6] = (f16)f1.z; dst[7] = (f16)f1.w;
}

// ======== MFMA GEMM 128x128 (R11-verified): BK=64 2-deep counted-vmcnt ======
template <int RELU, int RESH, int POS>
__global__ __launch_bounds__(256, 2) void k_gemm(
    const f16* __restrict__ A, const f16* __restrict__ WT,
    const float* __restrict__ bias, const f16* __restrict__ resH,
    const float* __restrict__ pos, f16* __restrict__ outH,
    int N, int K, int nwgx) {
  __shared__ f16 As[2][128 * 64];
  __shared__ f16 Bs[2][128 * 64];
  int tid = threadIdx.x;
  int wave = tid >> 6, lane = tid & 63;
  int wm = wave >> 1, wn = wave & 1;
  int nwg = gridDim.x;
  int id = blockIdx.x;
  int sw = (id & 7) * (nwg >> 3) + (id >> 3);
  int m0 = (sw / nwgx) * 128, n0 = (sw % nwgx) * 128;
  f32x4 acc[4][4] = {};
  int lrow = lane & 15;
  int rs_ = tid >> 3, js = tid & 7;
  int gc = (js ^ (rs_ & 7)) * 8;
  int e = tid * 8;
  int kq = lane >> 4;

  auto STAGE = [&](int buf, int k0) {
#pragma unroll
    for (int q = 0; q < 4; q++)
      gl_lds16(&A [(long)(m0 + q * 32 + rs_) * K + k0 + gc], &As[buf][q * 2048 + e]);
#pragma unroll
    for (int q = 0; q < 4; q++)
      gl_lds16(&WT[(long)(n0 + q * 32 + rs_) * K + k0 + gc], &Bs[buf][q * 2048 + e]);
  };

  int nIter = K >> 6;
  STAGE(0, 0); STAGE(1, 64);
  int cur = 0;
  int kc0 = (kq ^ (lrow & 7)) * 8;
  int kc1 = ((4 + kq) ^ (lrow & 7)) * 8;
  for (int it = 0; it < nIter; ++it) {
    if (it + 1 < nIter) VMCNT(8);
    else               VMCNT(0);
    __builtin_amdgcn_s_barrier();
    f16x8 af[2][4], bfr[2][4];
#pragma unroll
    for (int i = 0; i < 4; i++) {
      af[0][i]  = *reinterpret_cast<const f16x8*>(&As[cur][(wm * 64 + i * 16 + lrow) * 64 + kc0]);
      bfr[0][i] = *reinterpret_cast<const f16x8*>(&Bs[cur][(wn * 64 + i * 16 + lrow) * 64 + kc0]);
    }
    __builtin_amdgcn_sched_barrier(0);
#pragma unroll
    for (int i = 0; i < 4; i++) {
      af[1][i]  = *reinterpret_cast<const f16x8*>(&As[cur][(wm * 64 + i * 16 + lrow) * 64 + kc1]);
      bfr[1][i] = *reinterpret_cast<const f16x8*>(&Bs[cur][(wn * 64 + i * 16 + lrow) * 64 + kc1]);
    }
    asm volatile("s_waitcnt lgkmcnt(8)");
    __builtin_amdgcn_sched_barrier(0);
    __builtin_amdgcn_s_setprio(1);
#pragma unroll
    for (int i = 0; i < 4; i++)
#pragma unroll
      for (int j = 0; j < 4; j++)
        acc[i][j] = __builtin_amdgcn_mfma_f32_16x16x32_f16(af[0][i], bfr[0][j], acc[i][j], 0, 0, 0);
    __builtin_amdgcn_s_setprio(0);
    asm volatile("s_waitcnt lgkmcnt(0)");
    __builtin_amdgcn_sched_barrier(0);
    __builtin_amdgcn_s_barrier();
    if (it + 2 < nIter) STAGE(cur, (it + 2) << 6);
    __builtin_amdgcn_s_setprio(1);
#pragma unroll
    for (int i = 0; i < 4; i++)
#pragma unroll
      for (int j = 0; j < 4; j++)
        acc[i][j] = __builtin_amdgcn_mfma_f32_16x16x32_f16(af[1][i], bfr[1][j], acc[i][j], 0, 0, 0);
    __builtin_amdgcn_s_setprio(0);
    cur ^= 1;
  }
  int rq = lane >> 4;
#pragma unroll
  for (int i = 0; i < 4; i++) {
#pragma unroll
    for (int j = 0; j < 4; j++) {
      int col = n0 + wn * 64 + j * 16 + lrow;
      float bv = bias[col];
#pragma unroll
      for (int rr = 0; rr < 4; rr++) {
        int rowg = m0 + wm * 64 + i * 16 + rq * 4 + rr;
        float v = acc[i][j][rr] + bv;
        if (POS) v += pos[(rowg & 15) * EDIM + col];
        if (RESH) v += (float)resH[(long)rowg * N + col];
        if (RELU) v = fmaxf(v, 0.f);
        outH[(long)rowg * N + col] = (f16)v;
      }
    }
  }
}

// ======== MFMA GEMM 128x128, BK=32, 32KB LDS -> 4 blocks/CU (QKV probe) ======
// Tests whether per-CU LDS read throughput scales with resident waves.
// 64B rows, 4 chunks; both-sides XOR c^=(r&3) -> worst 2-way (free, m136).
__global__ __launch_bounds__(256, 4) void k_gemm_k32(
    const f16* __restrict__ A, const f16* __restrict__ WT,
    const float* __restrict__ bias, f16* __restrict__ outH,
    int N, int K, int nwgx) {
  __shared__ f16 As[2][128 * 32];
  __shared__ f16 Bs[2][128 * 32];
  int tid = threadIdx.x;
  int wave = tid >> 6, lane = tid & 63;
  int wm = wave >> 1, wn = wave & 1;
  int nwg = gridDim.x;
  int id = blockIdx.x;
  int sw = (id & 7) * (nwg >> 3) + (id >> 3);
  int m0 = (sw / nwgx) * 128, n0 = (sw % nwgx) * 128;
  f32x4 acc[4][4] = {};
  int lrow = lane & 15;
  int rs_ = tid >> 2, js = tid & 3;          // staging row 0..63 / chunk 0..3
  int gc = (js ^ (rs_ & 3)) * 8;             // swizzled global chunk
  int e = tid * 8;                           // LDS dest within 4KB issue
  int kq = lane >> 4;                        // frag k-chunk 0..3

  auto STAGE = [&](int buf, int k0) {
#pragma unroll
    for (int q = 0; q < 2; q++)
      gl_lds16(&A [(long)(m0 + q * 64 + rs_) * K + k0 + gc], &As[buf][q * 2048 + e]);
#pragma unroll
    for (int q = 0; q < 2; q++)
      gl_lds16(&WT[(long)(n0 + q * 64 + rs_) * K + k0 + gc], &Bs[buf][q * 2048 + e]);
  };

  int nIter = K >> 5;                        // K=512 -> 16
  STAGE(0, 0); STAGE(1, 32);
  int cur = 0;
  for (int it = 0; it < nIter; ++it) {
    if (it + 1 < nIter) VMCNT(4);            // buf[cur]'s 4 loads done
    else               VMCNT(0);
    __builtin_amdgcn_s_barrier();
    f16x8 af[4], bfr[4];
#pragma unroll
    for (int i = 0; i < 4; i++) {
      int ra = wm * 64 + i * 16 + lrow;
      int rb = wn * 64 + i * 16 + lrow;
      af[i]  = *reinterpret_cast<const f16x8*>(&As[cur][ra * 32 + ((kq ^ (ra & 3)) * 8)]);
      bfr[i] = *reinterpret_cast<const f16x8*>(&Bs[cur][rb * 32 + ((kq ^ (rb & 3)) * 8)]);
    }
    asm volatile("s_waitcnt lgkmcnt(0)");
    __builtin_amdgcn_sched_barrier(0);
    __builtin_amdgcn_s_barrier();            // all waves done reading buf[cur]
    if (it + 2 < nIter) STAGE(cur, (it + 2) << 5);
    __builtin_amdgcn_s_setprio(1);
#pragma unroll
    for (int i = 0; i < 4; i++)
#pragma unroll
      for (int j = 0; j < 4; j++)
        acc[i][j] = __builtin_amdgcn_mfma_f32_16x16x32_f16(af[i], bfr[j], acc[i][j], 0, 0, 0);
    __builtin_amdgcn_s_setprio(0);
    cur ^= 1;
  }
  int rq = lane >> 4;
#pragma unroll
  for (int i = 0; i < 4; i++) {
#pragma unroll
    for (int j = 0; j < 4; j++) {
      int col = n0 + wn * 64 + j * 16 + lrow;
      float bv = bias[col];
#pragma unroll
      for (int rr = 0; rr < 4; rr++) {
        int rowg = m0 + wm * 64 + i * 16 + rq * 4 + rr;
        outH[(long)rowg * N + col] = (f16)(acc[i][j][rr] + bv);
      }
    }
  }
}

// ======== MFMA GEMM 256x256 "big": used for W1 only (grid 512, clean) ======
template <int RELU>
__global__ __launch_bounds__(512, 1) void k_gemm_big(
    const f16* __restrict__ A, const f16* __restrict__ WT,
    const float* __restrict__ bias, f16* __restrict__ outH,
    int N, int K, int nwgx) {
  __shared__ f16 As[2][256 * 64];
  __shared__ f16 Bs[2][256 * 64];
  int tid = threadIdx.x;
  int wave = tid >> 6, lane = tid & 63;
  int wm = wave >> 2, wn = wave & 3;          // 2 x 4 wave grid
  int nwg = gridDim.x;
  int id = blockIdx.x;
  int sw = (id & 7) * (nwg >> 3) + (id >> 3);
  int m0 = (sw / nwgx) * 256, n0 = (sw % nwgx) * 256;
  f32x4 acc[8][4] = {};
  int lrow = lane & 15;
  int rs_ = tid >> 3, js = tid & 7;           // staging row 0..63 / chunk 0..7
  int gc = (js ^ (rs_ & 7)) * 8;
  int e = tid * 8;                            // 0..4095 elem per issue
  int kq = lane >> 4;

  auto STAGE = [&](int buf, int k0) {
#pragma unroll
    for (int q = 0; q < 4; q++)
      gl_lds16(&A [(long)(m0 + q * 64 + rs_) * K + k0 + gc], &As[buf][q * 4096 + e]);
#pragma unroll
    for (int q = 0; q < 4; q++)
      gl_lds16(&WT[(long)(n0 + q * 64 + rs_) * K + k0 + gc], &Bs[buf][q * 4096 + e]);
  };
  auto off = [&](int r, int c) {
    return ((r >> 6) << 12) + ((r & 63) << 6) + (((c ^ (r & 7)) & 7) << 3);
  };

  int nIter = K >> 6;
  STAGE(0, 0); STAGE(1, 64);
  int cur = 0;
  for (int it = 0; it < nIter; ++it) {
    if (it + 1 < nIter) VMCNT(8);
    else               VMCNT(0);
    __builtin_amdgcn_s_barrier();
    f16x8 af[8], bfr[4];
#pragma unroll
    for (int i = 0; i < 8; i++)
      af[i] = *reinterpret_cast<const f16x8*>(&As[cur][off(wm * 128 + i * 16 + lrow, kq)]);
#pragma unroll
    for (int j = 0; j < 4; j++)
      bfr[j] = *reinterpret_cast<const f16x8*>(&Bs[cur][off(wn * 64 + j * 16 + lrow, kq)]);
    asm volatile("s_waitcnt lgkmcnt(0)");
    __builtin_amdgcn_sched_barrier(0);
    __builtin_amdgcn_s_setprio(1);
#pragma unroll
    for (int i = 0; i < 8; i++)
#pragma unroll
      for (int j = 0; j < 4; j++)
        acc[i][j] = __builtin_amdgcn_mfma_f32_16x16x32_f16(af[i], bfr[j], acc[i][j], 0, 0, 0);
    __builtin_amdgcn_s_setprio(0);
#pragma unroll
    for (int i = 0; i < 8; i++)
      af[i] = *reinterpret_cast<const f16x8*>(&As[cur][off(wm * 128 + i * 16 + lrow, 4 + kq)]);
#pragma unroll
    for (int j = 0; j < 4; j++)
      bfr[j] = *reinterpret_cast<const f16x8*>(&Bs[cur][off(wn * 64 + j * 16 + lrow, 4 + kq)]);
    asm volatile("s_waitcnt lgkmcnt(0)");
    __builtin_amdgcn_sched_barrier(0);
    __builtin_amdgcn_s_barrier();              // all reads of buf[cur] done
    if (it + 2 < nIter) STAGE(cur, (it + 2) << 6);
    __builtin_amdgcn_s_setprio(1);
#pragma unroll
    for (int i = 0; i < 8; i++)
#pragma unroll
      for (int j = 0; j < 4; j++)
        acc[i][j] = __builtin_amdgcn_mfma_f32_16x16x32_f16(af[i], bfr[j], acc[i][j], 0, 0, 0);
    __builtin_amdgcn_s_setprio(0);
    cur ^= 1;
  }
  int rq = lane >> 4;
#pragma unroll
  for (int i = 0; i < 8; i++) {
#pragma unroll
    for (int j = 0; j < 4; j++) {
      int col = n0 + wn * 64 + j * 16 + lrow;
      float bv = bias[col];
#pragma unroll
      for (int rr = 0; rr < 4; rr++) {
        int rowg = m0 + wm * 128 + i * 16 + rq * 4 + rr;
        float v = acc[i][j][rr] + bv;
        if (RELU) v = fmaxf(v, 0.f);
        outH[(long)rowg * N + col] = (f16)v;
      }
    }
  }
}

// ======== spatial attention, MFMA: 1 block per frame, 4 waves x 2 heads ======
__global__ __launch_bounds__(256) void k_attn_spatial_mfma(const f16* __restrict__ qkv,
                                                           f16* __restrict__ o) {
  __shared__ f16 PT[4][32][18];     // per-wave P^T scratch, padded stride 18
  int frame = blockIdx.x;           // b*64+s
  int wave = threadIdx.x >> 6, lane = threadIdx.x & 63;
  int c = lane & 15, q = lane >> 4;
  int R0 = frame * 16;
  const f16* qb = qkv + (long)R0 * 1536;

  for (int z = lane; z < 32 * 18; z += 64) (&PT[wave][0][0])[z] = (f16)0.f;
  asm volatile("s_waitcnt lgkmcnt(0)");

#pragma unroll
  for (int hh = 0; hh < 2; hh++) {
    int h = wave * 2 + hh;
    const f16* hb = qb + h * 64;
    f32x4 s = {};
#pragma unroll
    for (int ks = 0; ks < 2; ks++) {
      f16x8 kf = *reinterpret_cast<const f16x8*>(hb + 512 + (long)c * 1536 + ks * 32 + 8 * q);
      f16x8 qf = *reinterpret_cast<const f16x8*>(hb + (long)c * 1536 + ks * 32 + 8 * q);
      s = __builtin_amdgcn_mfma_f32_16x16x32_f16(kf, qf, s, 0, 0, 0);
    }
    float mx = -1e30f;
#pragma unroll
    for (int r = 0; r < 4; r++) { s[r] *= 0.125f; mx = fmaxf(mx, s[r]); }
    mx = fmaxf(mx, __shfl_xor(mx, 16));
    mx = fmaxf(mx, __shfl_xor(mx, 32));
    float e[4], sum = 0.f;
#pragma unroll
    for (int r = 0; r < 4; r++) { e[r] = __expf(s[r] - mx); sum += e[r]; }
    sum += __shfl_xor(sum, 16);
    sum += __shfl_xor(sum, 32);
    float inv = 1.f / sum;
#pragma unroll
    for (int r = 0; r < 4; r++)
      PT[wave][4 * q + r][c] = (f16)(e[r] * inv);
    asm volatile("s_waitcnt lgkmcnt(0)");
    __builtin_amdgcn_sched_barrier(0);
    f16x8 af;
#pragma unroll
    for (int j = 0; j < 8; j++)
      af[j] = PT[wave][8 * q + j][c];   // rows>=16 are zero (K pad)
    asm volatile("s_waitcnt lgkmcnt(0)");
    __builtin_amdgcn_sched_barrier(0);
#pragma unroll
    for (int db = 0; db < 4; db++) {
      f16x8 vb;
#pragma unroll
      for (int j = 0; j < 8; j++) {
        int kp = (8 * q + j) & 15;
        vb[j] = hb[1024 + (long)kp * 1536 + db * 16 + c];
      }
      f32x4 oacc = {};
      oacc = __builtin_amdgcn_mfma_f32_16x16x32_f16(af, vb, oacc, 0, 0, 0);
#pragma unroll
      for (int r = 0; r < 4; r++)
        o[(long)(R0 + 4 * q + r) * EDIM + h * 64 + db * 16 + c] = (f16)oacc[r];
    }
  }
}

// ======== temporal causal attention, MFMA: 1 wave per (b, p, h); S=64, D=64 ====
__global__ __launch_bounds__(64) void k_attn_temporal_mfma(const f16* __restrict__ qkv,
                                                           f16* __restrict__ o) {
  __shared__ f16 Plds[64 * 72];
  __shared__ f16 VT[64 * 72];
  int bp = blockIdx.x >> 3, h = blockIdx.x & 7;
  int b = bp >> 4, p = bp & 15;
  int lane = threadIdx.x;
  int c = lane & 15, q = lane >> 4;
  const long RSTR = 16 * 1536;
  const f16* qb = qkv + ((long)(b * 1024 + p)) * 1536 + h * 64;

  {
    f16x8 z = {};
#pragma unroll
    for (int t = 0; t < 9; t++)
      *reinterpret_cast<f16x8*>(&Plds[(t * 64 + lane) * 8]) = z;
  }
#pragma unroll
  for (int t = 0; t < 8; t++) {
    int s = t * 8 + (lane >> 3), d0 = (lane & 7) * 8;
    f16x8 v = *reinterpret_cast<const f16x8*>(qb + 1024 + (long)s * RSTR + d0);
#pragma unroll
    for (int u = 0; u < 8; u++) {
      int d = d0 + u;
      VT[d * 72 + (s ^ (((d >> 3) & 7) << 3))] = v[u];
    }
  }
  __syncthreads();

  f32x4 sAcc[4][4] = {};
#pragma unroll
  for (int ks = 0; ks < 2; ks++) {
    f16x8 kf[4];
#pragma unroll
    for (int j = 0; j < 4; j++)
      kf[j] = *reinterpret_cast<const f16x8*>(qb + 512 + (long)(16 * j + c) * RSTR + 32 * ks + 8 * q);
#pragma unroll
    for (int i = 0; i < 4; i++) {
      f16x8 qf = *reinterpret_cast<const f16x8*>(qb + (long)(16 * i + c) * RSTR + 32 * ks + 8 * q);
#pragma unroll
      for (int j = 0; j < 4; j++)
        if (j <= i)
          sAcc[i][j] = __builtin_amdgcn_mfma_f32_16x16x32_f16(qf, kf[j], sAcc[i][j], 0, 0, 0);
    }
  }

  f32x4 invs[4];
#pragma unroll
  for (int i = 0; i < 4; i++) {
    f32x4 mx;
#pragma unroll
    for (int r = 0; r < 4; r++) mx[r] = -1e30f;
#pragma unroll
    for (int j = 0; j <= i; j++)
#pragma unroll
      for (int r = 0; r < 4; r++) {
        float v = sAcc[i][j][r] * 0.125f;
        if (j == i && c > 4 * q + r) v = -1e30f;
        sAcc[i][j][r] = v;
        mx[r] = fmaxf(mx[r], v);
      }
#pragma unroll
    for (int off = 1; off < 16; off <<= 1)
#pragma unroll
      for (int r = 0; r < 4; r++) mx[r] = fmaxf(mx[r], __shfl_xor(mx[r], off));
    f32x4 sm = {};
#pragma unroll
    for (int j = 0; j <= i; j++)
#pragma unroll
      for (int r = 0; r < 4; r++) {
        float e = __expf(sAcc[i][j][r] - mx[r]);
        sm[r] += e;
        Plds[(16 * i + 4 * q + r) * 72 + 16 * j + c] = (f16)e;
      }
#pragma unroll
    for (int off = 1; off < 16; off <<= 1)
#pragma unroll
      for (int r = 0; r < 4; r++) sm[r] += __shfl_xor(sm[r], off);
#pragma unroll
    for (int r = 0; r < 4; r++) invs[i][r] = 1.f / sm[r];
  }
  __syncthreads();

  f32x4 oacc[4][4] = {};
#pragma unroll
  for (int kb = 0; kb < 2; kb++) {
    f16x8 vb[4];
#pragma unroll
    for (int db = 0; db < 4; db++) {
      int d = 16 * db + c;
      vb[db] = *reinterpret_cast<const f16x8*>(&VT[d * 72 + ((32 * kb + 8 * q) ^ (((d >> 3) & 7) << 3))]);
    }
#pragma unroll
    for (int i = 0; i < 4; i++) {
      if (kb == 1 && i < 2) continue;
      f16x8 pa = *reinterpret_cast<const f16x8*>(&Plds[(16 * i + c) * 72 + 32 * kb + 8 * q]);
#pragma unroll
      for (int db = 0; db < 4; db++)
        oacc[i][db] = __builtin_amdgcn_mfma_f32_16x16x32_f16(pa, vb[db], oacc[i][db], 0, 0, 0);
    }
  }

#pragma unroll
  for (int i = 0; i < 4; i++)
#pragma unroll
    for (int db = 0; db < 4; db++)
#pragma unroll
      for (int r = 0; r < 4; r++) {
        int srow = 16 * i + 4 * q + r;
        long tok = (long)(b * 64 + srow) * 16 + p;
        o[tok * EDIM + h * 64 + 16 * db + c] = (f16)(oacc[i][db][r] * invs[i][r]);
      }
}

// ======== LayerNorm over 512 (fp16 in): 4 rows per 256-thr block ========
template <int FINAL>
__global__ __launch_bounds__(256) void k_ln_h(const f16* __restrict__ r,
                                              const float* __restrict__ g,
                                              const float* __restrict__ b,
                                              float* __restrict__ xf,
                                              f16* __restrict__ xh) {
  int row = blockIdx.x * 4 + (threadIdx.x >> 6);
  int lane = threadIdx.x & 63;
  f16x8 v = *reinterpret_cast<const f16x8*>(r + (long)row * EDIM + lane * 8);
  float vals[8];
  float s = 0.f, q = 0.f;
#pragma unroll
  for (int u = 0; u < 8; u++) {
    vals[u] = (float)v[u];
    s += vals[u]; q += vals[u] * vals[u];
  }
#pragma unroll
  for (int off = 32; off; off >>= 1) { s += __shfl_xor(s, off); q += __shfl_xor(q, off); }
  float mean = s * (1.f / EDIM);
  float var = q * (1.f / EDIM) - mean * mean;
  float rs = rsqrtf(var + 1e-5f);
  long base = (long)row * EDIM + lane * 8;
  if (FINAL) {
#pragma unroll
    for (int u = 0; u < 8; u++) {
      int cidx = lane * 8 + u;
      xf[base + u] = (vals[u] - mean) * rs * g[cidx] + b[cidx];
    }
  } else {
    f16x8 y;
#pragma unroll
    for (int u = 0; u < 8; u++) {
      int cidx = lane * 8 + u;
      y[u] = (f16)((vals[u] - mean) * rs * g[cidx] + b[cidx]);
    }
    *reinterpret_cast<f16x8*>(xh + base) = y;
  }
}

// ======== head: pool over patches, pair-concat, LN(1024), @ h_w + h_b ========
__global__ __launch_bounds__(256) void k_head(const float* __restrict__ xf,
                                              const float* __restrict__ g,
                                              const float* __restrict__ b,
                                              const float* __restrict__ hw,
                                              const float* __restrict__ hb,
                                              float* __restrict__ actions) {
  __shared__ float lnv[1024];
  __shared__ float red[10];
  int blk = blockIdx.x;               // 16*63
  int bb = blk / 63, t = blk % 63;
  int tid = threadIdx.x;
  float vals[4];
  float s = 0.f, q = 0.f;
#pragma unroll
  for (int u = 0; u < 4; u++) {
    int idx = tid * 4 + u;            // 0..1023
    int half = idx >> 9, e = idx & 511;
    const float* base = xf + (long)(((bb * 64) + t + half) * 16) * EDIM + e;
    float acc = 0.f;
#pragma unroll
    for (int p = 0; p < 16; p++) acc += base[p * EDIM];
    acc *= (1.f / 16.f);
    vals[u] = acc; s += acc; q += acc * acc;
  }
#pragma unroll
  for (int off = 32; off; off >>= 1) { s += __shfl_xor(s, off); q += __shfl_xor(q, off); }
  if ((tid & 63) == 0) { red[tid >> 6] = s; red[4 + (tid >> 6)] = q; }
  __syncthreads();
  if (tid == 0) {
    float S = red[0] + red[1] + red[2] + red[3];
    float Q = red[4] + red[5] + red[6] + red[7];
    float m = S * (1.f / 1024.f);
    red[8] = m;
    red[9] = rsqrtf(Q * (1.f / 1024.f) - m * m + 1e-5f);
  }
  __syncthreads();
  float m = red[8], rs = red[9];
#pragma unroll
  for (int u = 0; u < 4; u++) {
    int idx = tid * 4 + u;
    lnv[idx] = (vals[u] - m) * rs * g[idx] + b[idx];
  }
  __syncthreads();
  if (tid < 64) {
    float acc = hb[tid];
    for (int e = 0; e < 1024; e++) acc += lnv[e] * hw[e * 64 + tid];
    actions[(long)blk * 64 + tid] = acc;
  }
}

extern "C" void kernel_launch(void* const* d_in, const int* in_sizes, int n_in,
                              void* d_out, int out_size, void* d_ws, size_t ws_size,
                              hipStream_t stream) {
  (void)in_sizes; (void)n_in; (void)out_size; (void)ws_size;
  const float* frames  = (const float*)d_in[0];
  const float* w_patch = (const float*)d_in[1];
  const float* b_patch = (const float*)d_in[2];
  const float* pos     = (const float*)d_in[3];
  const float* s_w[4]  = {(const float*)d_in[4],  (const float*)d_in[5],
                          (const float*)d_in[6],  (const float*)d_in[7]};
  const float* s_bq = (const float*)d_in[8];
  const float* s_bk = (const float*)d_in[9];
  const float* s_bv = (const float*)d_in[10];
  const float* s_bo = (const float*)d_in[11];
  const float* s_lng = (const float*)d_in[12];
  const float* s_lnb = (const float*)d_in[13];
  const float* t_w[4]  = {(const float*)d_in[14], (const float*)d_in[15],
                          (const float*)d_in[16], (const float*)d_in[17]};
  const float* t_bq = (const float*)d_in[18];
  const float* t_bk = (const float*)d_in[19];
  const float* t_bv = (const float*)d_in[20];
  const float* t_bo = (const float*)d_in[21];
  const float* t_lng = (const float*)d_in[22];
  const float* t_lnb = (const float*)d_in[23];
  const float* f_w1 = (const float*)d_in[24];
  const float* f_b1 = (const float*)d_in[25];
  const float* f_w2 = (const float*)d_in[26];
  const float* f_b2 = (const float*)d_in[27];
  const float* f_lng = (const float*)d_in[28];
  const float* f_lnb = (const float*)d_in[29];
  const float* h_lng = (const float*)d_in[30];
  const float* h_lnb = (const float*)d_in[31];
  const float* h_w = (const float*)d_in[32];
  const float* h_b = (const float*)d_in[33];

  char* ws = (char*)d_ws;
  size_t off = 0;
  auto alloc = [&](size_t bytes) { size_t o = off; off += (bytes + 255) & ~(size_t)255; return o; };
  f16* sqkvT = (f16*)(ws + alloc((size_t)6 * 1536 * 512 * 2));
  f16* swoT  = (f16*)(ws + alloc((size_t)6 * 512 * 512 * 2));
  f16* tqkvT = (f16*)(ws + alloc((size_t)6 * 1536 * 512 * 2));
  f16* twoT  = (f16*)(ws + alloc((size_t)6 * 512 * 512 * 2));
  f16* w1T   = (f16*)(ws + alloc((size_t)6 * 2048 * 512 * 2));
  f16* w2T   = (f16*)(ws + alloc((size_t)6 * 512 * 2048 * 2));
  f16* wpT   = (f16*)(ws + alloc((size_t)512 * 768 * 2));
  float* bqkv = (float*)(ws + alloc((size_t)2 * 6 * 1536 * 4));
  f16* xh    = (f16*)(ws + alloc((size_t)NTOK * EDIM * 2));
  char* regC = ws + alloc((size_t)NTOK * 1536 * 2);   // qkv | rbufH (phase-disjoint)
  char* regD = ws + alloc((size_t)NTOK * 2048 * 2);   // P | o | h1 (phase-disjoint)
  f16* qkv   = (f16*)regC;
  f16* rbufH = (f16*)regC;
  f16* Pmat  = (f16*)regD;
  f16* obuf  = (f16*)regD;
  f16* h1    = (f16*)regD;

  dim3 tb(32, 8);
  for (int pre = 0; pre < 2; pre++) {
    const float* const* wsrc = pre ? t_w : s_w;
    f16* qdst = pre ? tqkvT : sqkvT;
    f16* odst = pre ? twoT : swoT;
    for (int wi = 0; wi < 3; wi++)
      k_transpose<<<dim3(16, 16, 6), tb, 0, stream>>>(wsrc[wi], qdst + wi * 512 * 512,
                                                      512, 512, 262144L, 786432L);
    k_transpose<<<dim3(16, 16, 6), tb, 0, stream>>>(wsrc[3], odst, 512, 512, 262144L, 262144L);
  }
  k_transpose<<<dim3(64, 16, 6), tb, 0, stream>>>(f_w1, w1T, 512, 2048, 1048576L, 1048576L);
  k_transpose<<<dim3(16, 64, 6), tb, 0, stream>>>(f_w2, w2T, 2048, 512, 1048576L, 1048576L);
  k_transpose<<<dim3(16, 24, 1), tb, 0, stream>>>(w_patch, wpT, 768, 512, 0L, 0L);
  k_pack_bias<<<72, 256, 0, stream>>>(s_bq, s_bk, s_bv, t_bq, t_bk, t_bv, bqkv);

  k_patchify<<<6144, 256, 0, stream>>>(frames, Pmat);
  // grids: all 1D, count % 8 == 0 (bijective XCD swizzle requirement)
  k_gemm<0, 0, 1><<<512, 256, 0, stream>>>(
      Pmat, wpT, b_patch, nullptr, pos, xh, 512, 768, 4);

  float* out = (float*)d_out;
  float* xf_final = out + 64512;   // second output: x fp32, written by final LN

  for (int l = 0; l < 6; l++) {
    // ---- spatial attention ----
    k_gemm_k32<<<1536, 256, 0, stream>>>(
        xh, sqkvT + (size_t)l * 1536 * 512, bqkv + l * 1536, qkv, 1536, 512, 12);
    k_attn_spatial_mfma<<<1024, 256, 0, stream>>>(qkv, obuf);
    k_gemm<0, 1, 0><<<512, 256, 0, stream>>>(
        obuf, swoT + (size_t)l * 512 * 512, s_bo + l * 512,
        xh, nullptr, rbufH, 512, 512, 4);
    k_ln_h<0><<<NTOK / 4, 256, 0, stream>>>(rbufH, s_lng + l * 512, s_lnb + l * 512,
                                            nullptr, xh);
    // ---- temporal attention ----
    k_gemm_k32<<<1536, 256, 0, stream>>>(
        xh, tqkvT + (size_t)l * 1536 * 512, bqkv + (6 + l) * 1536, qkv, 1536, 512, 12);
    k_attn_temporal_mfma<<<2048, 64, 0, stream>>>(qkv, obuf);
    k_gemm<0, 1, 0><<<512, 256, 0, stream>>>(
        obuf, twoT + (size_t)l * 512 * 512, t_bo + l * 512,
        xh, nullptr, rbufH, 512, 512, 4);
    k_ln_h<0><<<NTOK / 4, 256, 0, stream>>>(rbufH, t_lng + l * 512, t_lnb + l * 512,
                                            nullptr, xh);
    // ---- FFN ----
    k_gemm_big<1><<<512, 512, 0, stream>>>(
        xh, w1T + (size_t)l * 2048 * 512, f_b1 + l * 2048, h1, 2048, 512, 8);
    k_gemm<0, 1, 0><<<512, 256, 0, stream>>>(
        h1, w2T + (size_t)l * 512 * 2048, f_b2 + l * 512,
        xh, nullptr, rbufH, 512, 2048, 4);
    if (l == 5) {
      k_ln_h<1><<<NTOK / 4, 256, 0, stream>>>(rbufH, f_lng + l * 512, f_lnb + l * 512,
                                              xf_final, nullptr);
    } else {
      k_ln_h<0><<<NTOK / 4, 256, 0, stream>>>(rbufH, f_lng + l * 512, f_lnb + l * 512,
                                              nullptr, xh);
    }
  }

  k_head<<<1008, 256, 0, stream>>>(xf_final, h_lng, h_lnb, h_w, h_b, out);
}

// Round 18
// 1756.166 us; speedup vs baseline: 1.0062x; 1.0062x over previous
//
#include <hip/hip_runtime.h>
#include <hip/hip_bf16.h>

typedef _Float16 f16;
typedef _Float16 f16x8 __attribute__((ext_vector_type(8)));
typedef float f32x4 __attribute__((ext_vector_type(4)));

#define NTOK 16384   // 16*64*16 tokens
#define EDIM 512
#define FFDIM 2048
#define PDIM 768

#define VMCNT(n) asm volatile("s_waitcnt vmcnt(" #n ")")

// async global->LDS DMA, 16B per lane. LDS dest must be linear in lane order.
typedef __attribute__((address_space(3))) unsigned int lds_uint;
typedef __attribute__((address_space(1))) const unsigned int glob_uint;
__device__ __forceinline__ void gl_lds16(const f16* g, f16* l) {
  __builtin_amdgcn_global_load_lds((glob_uint*)g, (lds_uint*)l, 16, 0, 0);
}

// ======== weight transpose: fp32 [B][R][C] -> fp16 [B][C][R] ========
__global__ void k_transpose(const float* __restrict__ src, f16* __restrict__ dst,
                            int R, int C, long srcBS, long dstBS) {
  __shared__ float tile[32][33];
  src += (long)blockIdx.z * srcBS;
  dst += (long)blockIdx.z * dstBS;
  int c0 = blockIdx.x * 32, r0 = blockIdx.y * 32;
  int tx = threadIdx.x, ty = threadIdx.y;
#pragma unroll
  for (int j = ty; j < 32; j += 8)
    tile[j][tx] = src[(long)(r0 + j) * C + (c0 + tx)];
  __syncthreads();
#pragma unroll
  for (int j = ty; j < 32; j += 8)
    dst[(long)(c0 + j) * R + (r0 + tx)] = (f16)tile[tx][j];
}

// ======== pack QKV biases -> [2][6][1536] fp32 ========
__global__ void k_pack_bias(const float* __restrict__ sq, const float* __restrict__ sk,
                            const float* __restrict__ sv, const float* __restrict__ tq,
                            const float* __restrict__ tk, const float* __restrict__ tv,
                            float* __restrict__ dst) {
  int i = blockIdx.x * 256 + threadIdx.x;
  if (i >= 2 * 6 * 1536) return;
  int pre = i / (6 * 1536), rem = i % (6 * 1536), l = rem / 1536, e = rem % 1536;
  const float* s;
  if (pre == 0) s = (e < 512) ? sq : (e < 1024) ? sk : sv;
  else          s = (e < 512) ? tq : (e < 1024) ? tk : tv;
  dst[i] = s[l * 512 + (e & 511)];
}

// ======== patchify: frames fp32 [16][64][3][64][64] -> P fp16 [16384][768] ========
__global__ void k_patchify(const float* __restrict__ frames, f16* __restrict__ P) {
  int gid = blockIdx.x * 256 + threadIdx.x;           // < 16384*96
  int token = gid / 96, chunk = gid % 96;
  int b = token >> 10, s = (token >> 4) & 63, p = token & 15;
  int c = chunk >> 5, rem = chunk & 31, p1 = rem >> 1, p2b = (rem & 1) * 8;
  int h = p >> 2, w = p & 3;
  const float* src = frames + ((long)(((b * 64 + s) * 3 + c) * 64 + h * 16 + p1)) * 64 + w * 16 + p2b;
  float4 f0 = *reinterpret_cast<const float4*>(src);
  float4 f1 = *reinterpret_cast<const float4*>(src + 4);
  f16* dst = P + (long)token * PDIM + chunk * 8;
  dst[0] = (f16)f0.x; dst[1] = (f16)f0.y; dst[2] = (f16)f0.z; dst[3] = (f16)f0.w;
  dst[4] = (f16)f1.x; dst[5] = (f16)f1.y; dst[6] = (f16)f1.z; dst[7] = (f16)f1.w;
}

// ======== MFMA GEMM 128x128 (R11-verified): BK=64 2-deep counted-vmcnt ======
template <int RELU, int RESH, int POS>
__global__ __launch_bounds__(256, 2) void k_gemm(
    const f16* __restrict__ A, const f16* __restrict__ WT,
    const float* __restrict__ bias, const f16* __restrict__ resH,
    const float* __restrict__ pos, f16* __restrict__ outH,
    int N, int K, int nwgx) {
  __shared__ f16 As[2][128 * 64];
  __shared__ f16 Bs[2][128 * 64];
  int tid = threadIdx.x;
  int wave = tid >> 6, lane = tid & 63;
  int wm = wave >> 1, wn = wave & 1;
  int nwg = gridDim.x;
  int id = blockIdx.x;
  int sw = (id & 7) * (nwg >> 3) + (id >> 3);
  int m0 = (sw / nwgx) * 128, n0 = (sw % nwgx) * 128;
  f32x4 acc[4][4] = {};
  int lrow = lane & 15;
  int rs_ = tid >> 3, js = tid & 7;
  int gc = (js ^ (rs_ & 7)) * 8;
  int e = tid * 8;
  int kq = lane >> 4;

  auto STAGE = [&](int buf, int k0) {
#pragma unroll
    for (int q = 0; q < 4; q++)
      gl_lds16(&A [(long)(m0 + q * 32 + rs_) * K + k0 + gc], &As[buf][q * 2048 + e]);
#pragma unroll
    for (int q = 0; q < 4; q++)
      gl_lds16(&WT[(long)(n0 + q * 32 + rs_) * K + k0 + gc], &Bs[buf][q * 2048 + e]);
  };

  int nIter = K >> 6;
  STAGE(0, 0); STAGE(1, 64);
  int cur = 0;
  int kc0 = (kq ^ (lrow & 7)) * 8;
  int kc1 = ((4 + kq) ^ (lrow & 7)) * 8;
  for (int it = 0; it < nIter; ++it) {
    if (it + 1 < nIter) VMCNT(8);
    else               VMCNT(0);
    __builtin_amdgcn_s_barrier();
    f16x8 af[2][4], bfr[2][4];
#pragma unroll
    for (int i = 0; i < 4; i++) {
      af[0][i]  = *reinterpret_cast<const f16x8*>(&As[cur][(wm * 64 + i * 16 + lrow) * 64 + kc0]);
      bfr[0][i] = *reinterpret_cast<const f16x8*>(&Bs[cur][(wn * 64 + i * 16 + lrow) * 64 + kc0]);
    }
    __builtin_amdgcn_sched_barrier(0);
#pragma unroll
    for (int i = 0; i < 4; i++) {
      af[1][i]  = *reinterpret_cast<const f16x8*>(&As[cur][(wm * 64 + i * 16 + lrow) * 64 + kc1]);
      bfr[1][i] = *reinterpret_cast<const f16x8*>(&Bs[cur][(wn * 64 + i * 16 + lrow) * 64 + kc1]);
    }
    asm volatile("s_waitcnt lgkmcnt(8)");
    __builtin_amdgcn_sched_barrier(0);
    __builtin_amdgcn_s_setprio(1);
#pragma unroll
    for (int i = 0; i < 4; i++)
#pragma unroll
      for (int j = 0; j < 4; j++)
        acc[i][j] = __builtin_amdgcn_mfma_f32_16x16x32_f16(af[0][i], bfr[0][j], acc[i][j], 0, 0, 0);
    __builtin_amdgcn_s_setprio(0);
    asm volatile("s_waitcnt lgkmcnt(0)");
    __builtin_amdgcn_sched_barrier(0);
    __builtin_amdgcn_s_barrier();
    if (it + 2 < nIter) STAGE(cur, (it + 2) << 6);
    __builtin_amdgcn_s_setprio(1);
#pragma unroll
    for (int i = 0; i < 4; i++)
#pragma unroll
      for (int j = 0; j < 4; j++)
        acc[i][j] = __builtin_amdgcn_mfma_f32_16x16x32_f16(af[1][i], bfr[1][j], acc[i][j], 0, 0, 0);
    __builtin_amdgcn_s_setprio(0);
    cur ^= 1;
  }
  int rq = lane >> 4;
#pragma unroll
  for (int i = 0; i < 4; i++) {
#pragma unroll
    for (int j = 0; j < 4; j++) {
      int col = n0 + wn * 64 + j * 16 + lrow;
      float bv = bias[col];
#pragma unroll
      for (int rr = 0; rr < 4; rr++) {
        int rowg = m0 + wm * 64 + i * 16 + rq * 4 + rr;
        float v = acc[i][j][rr] + bv;
        if (POS) v += pos[(rowg & 15) * EDIM + col];
        if (RESH) v += (float)resH[(long)rowg * N + col];
        if (RELU) v = fmaxf(v, 0.f);
        outH[(long)rowg * N + col] = (f16)v;
      }
    }
  }
}

// ======== MFMA GEMM 256x256 "big": used for W1 only (grid 512, clean) ======
template <int RELU>
__global__ __launch_bounds__(512, 1) void k_gemm_big(
    const f16* __restrict__ A, const f16* __restrict__ WT,
    const float* __restrict__ bias, f16* __restrict__ outH,
    int N, int K, int nwgx) {
  __shared__ f16 As[2][256 * 64];
  __shared__ f16 Bs[2][256 * 64];
  int tid = threadIdx.x;
  int wave = tid >> 6, lane = tid & 63;
  int wm = wave >> 2, wn = wave & 3;          // 2 x 4 wave grid
  int nwg = gridDim.x;
  int id = blockIdx.x;
  int sw = (id & 7) * (nwg >> 3) + (id >> 3);
  int m0 = (sw / nwgx) * 256, n0 = (sw % nwgx) * 256;
  f32x4 acc[8][4] = {};
  int lrow = lane & 15;
  int rs_ = tid >> 3, js = tid & 7;           // staging row 0..63 / chunk 0..7
  int gc = (js ^ (rs_ & 7)) * 8;
  int e = tid * 8;                            // 0..4095 elem per issue
  int kq = lane >> 4;

  auto STAGE = [&](int buf, int k0) {
#pragma unroll
    for (int q = 0; q < 4; q++)
      gl_lds16(&A [(long)(m0 + q * 64 + rs_) * K + k0 + gc], &As[buf][q * 4096 + e]);
#pragma unroll
    for (int q = 0; q < 4; q++)
      gl_lds16(&WT[(long)(n0 + q * 64 + rs_) * K + k0 + gc], &Bs[buf][q * 4096 + e]);
  };
  auto off = [&](int r, int c) {
    return ((r >> 6) << 12) + ((r & 63) << 6) + (((c ^ (r & 7)) & 7) << 3);
  };

  int nIter = K >> 6;
  STAGE(0, 0); STAGE(1, 64);
  int cur = 0;
  for (int it = 0; it < nIter; ++it) {
    if (it + 1 < nIter) VMCNT(8);
    else               VMCNT(0);
    __builtin_amdgcn_s_barrier();
    f16x8 af[8], bfr[4];
#pragma unroll
    for (int i = 0; i < 8; i++)
      af[i] = *reinterpret_cast<const f16x8*>(&As[cur][off(wm * 128 + i * 16 + lrow, kq)]);
#pragma unroll
    for (int j = 0; j < 4; j++)
      bfr[j] = *reinterpret_cast<const f16x8*>(&Bs[cur][off(wn * 64 + j * 16 + lrow, kq)]);
    asm volatile("s_waitcnt lgkmcnt(0)");
    __builtin_amdgcn_sched_barrier(0);
    __builtin_amdgcn_s_setprio(1);
#pragma unroll
    for (int i = 0; i < 8; i++)
#pragma unroll
      for (int j = 0; j < 4; j++)
        acc[i][j] = __builtin_amdgcn_mfma_f32_16x16x32_f16(af[i], bfr[j], acc[i][j], 0, 0, 0);
    __builtin_amdgcn_s_setprio(0);
#pragma unroll
    for (int i = 0; i < 8; i++)
      af[i] = *reinterpret_cast<const f16x8*>(&As[cur][off(wm * 128 + i * 16 + lrow, 4 + kq)]);
#pragma unroll
    for (int j = 0; j < 4; j++)
      bfr[j] = *reinterpret_cast<const f16x8*>(&Bs[cur][off(wn * 64 + j * 16 + lrow, 4 + kq)]);
    asm volatile("s_waitcnt lgkmcnt(0)");
    __builtin_amdgcn_sched_barrier(0);
    __builtin_amdgcn_s_barrier();              // all reads of buf[cur] done
    if (it + 2 < nIter) STAGE(cur, (it + 2) << 6);
    __builtin_amdgcn_s_setprio(1);
#pragma unroll
    for (int i = 0; i < 8; i++)
#pragma unroll
      for (int j = 0; j < 4; j++)
        acc[i][j] = __builtin_amdgcn_mfma_f32_16x16x32_f16(af[i], bfr[j], acc[i][j], 0, 0, 0);
    __builtin_amdgcn_s_setprio(0);
    cur ^= 1;
  }
  int rq = lane >> 4;
#pragma unroll
  for (int i = 0; i < 8; i++) {
#pragma unroll
    for (int j = 0; j < 4; j++) {
      int col = n0 + wn * 64 + j * 16 + lrow;
      float bv = bias[col];
#pragma unroll
      for (int rr = 0; rr < 4; rr++) {
        int rowg = m0 + wm * 128 + i * 16 + rq * 4 + rr;
        float v = acc[i][j][rr] + bv;
        if (RELU) v = fmaxf(v, 0.f);
        outH[(long)rowg * N + col] = (f16)v;
      }
    }
  }
}

// ======== spatial attention, MFMA: 1 block per frame, 4 waves x 2 heads ======
__global__ __launch_bounds__(256) void k_attn_spatial_mfma(const f16* __restrict__ qkv,
                                                           f16* __restrict__ o) {
  __shared__ f16 PT[4][32][18];     // per-wave P^T scratch, padded stride 18
  int frame = blockIdx.x;           // b*64+s
  int wave = threadIdx.x >> 6, lane = threadIdx.x & 63;
  int c = lane & 15, q = lane >> 4;
  int R0 = frame * 16;
  const f16* qb = qkv + (long)R0 * 1536;

  for (int z = lane; z < 32 * 18; z += 64) (&PT[wave][0][0])[z] = (f16)0.f;
  asm volatile("s_waitcnt lgkmcnt(0)");

#pragma unroll
  for (int hh = 0; hh < 2; hh++) {
    int h = wave * 2 + hh;
    const f16* hb = qb + h * 64;
    f32x4 s = {};
#pragma unroll
    for (int ks = 0; ks < 2; ks++) {
      f16x8 kf = *reinterpret_cast<const f16x8*>(hb + 512 + (long)c * 1536 + ks * 32 + 8 * q);
      f16x8 qf = *reinterpret_cast<const f16x8*>(hb + (long)c * 1536 + ks * 32 + 8 * q);
      s = __builtin_amdgcn_mfma_f32_16x16x32_f16(kf, qf, s, 0, 0, 0);
    }
    float mx = -1e30f;
#pragma unroll
    for (int r = 0; r < 4; r++) { s[r] *= 0.125f; mx = fmaxf(mx, s[r]); }
    mx = fmaxf(mx, __shfl_xor(mx, 16));
    mx = fmaxf(mx, __shfl_xor(mx, 32));
    float e[4], sum = 0.f;
#pragma unroll
    for (int r = 0; r < 4; r++) { e[r] = __expf(s[r] - mx); sum += e[r]; }
    sum += __shfl_xor(sum, 16);
    sum += __shfl_xor(sum, 32);
    float inv = 1.f / sum;
#pragma unroll
    for (int r = 0; r < 4; r++)
      PT[wave][4 * q + r][c] = (f16)(e[r] * inv);
    asm volatile("s_waitcnt lgkmcnt(0)");
    __builtin_amdgcn_sched_barrier(0);
    f16x8 af;
#pragma unroll
    for (int j = 0; j < 8; j++)
      af[j] = PT[wave][8 * q + j][c];   // rows>=16 are zero (K pad)
    asm volatile("s_waitcnt lgkmcnt(0)");
    __builtin_amdgcn_sched_barrier(0);
#pragma unroll
    for (int db = 0; db < 4; db++) {
      f16x8 vb;
#pragma unroll
      for (int j = 0; j < 8; j++) {
        int kp = (8 * q + j) & 15;
        vb[j] = hb[1024 + (long)kp * 1536 + db * 16 + c];
      }
      f32x4 oacc = {};
      oacc = __builtin_amdgcn_mfma_f32_16x16x32_f16(af, vb, oacc, 0, 0, 0);
#pragma unroll
      for (int r = 0; r < 4; r++)
        o[(long)(R0 + 4 * q + r) * EDIM + h * 64 + db * 16 + c] = (f16)oacc[r];
    }
  }
}

// ======== temporal causal attention, MFMA: 1 wave per (b, p, h); S=64, D=64 ====
__global__ __launch_bounds__(64) void k_attn_temporal_mfma(const f16* __restrict__ qkv,
                                                           f16* __restrict__ o) {
  __shared__ f16 Plds[64 * 72];
  __shared__ f16 VT[64 * 72];
  int bp = blockIdx.x >> 3, h = blockIdx.x & 7;
  int b = bp >> 4, p = bp & 15;
  int lane = threadIdx.x;
  int c = lane & 15, q = lane >> 4;
  const long RSTR = 16 * 1536;
  const f16* qb = qkv + ((long)(b * 1024 + p)) * 1536 + h * 64;

  {
    f16x8 z = {};
#pragma unroll
    for (int t = 0; t < 9; t++)
      *reinterpret_cast<f16x8*>(&Plds[(t * 64 + lane) * 8]) = z;
  }
#pragma unroll
  for (int t = 0; t < 8; t++) {
    int s = t * 8 + (lane >> 3), d0 = (lane & 7) * 8;
    f16x8 v = *reinterpret_cast<const f16x8*>(qb + 1024 + (long)s * RSTR + d0);
#pragma unroll
    for (int u = 0; u < 8; u++) {
      int d = d0 + u;
      VT[d * 72 + (s ^ (((d >> 3) & 7) << 3))] = v[u];
    }
  }
  __syncthreads();

  f32x4 sAcc[4][4] = {};
#pragma unroll
  for (int ks = 0; ks < 2; ks++) {
    f16x8 kf[4];
#pragma unroll
    for (int j = 0; j < 4; j++)
      kf[j] = *reinterpret_cast<const f16x8*>(qb + 512 + (long)(16 * j + c) * RSTR + 32 * ks + 8 * q);
#pragma unroll
    for (int i = 0; i < 4; i++) {
      f16x8 qf = *reinterpret_cast<const f16x8*>(qb + (long)(16 * i + c) * RSTR + 32 * ks + 8 * q);
#pragma unroll
      for (int j = 0; j < 4; j++)
        if (j <= i)
          sAcc[i][j] = __builtin_amdgcn_mfma_f32_16x16x32_f16(qf, kf[j], sAcc[i][j], 0, 0, 0);
    }
  }

  f32x4 invs[4];
#pragma unroll
  for (int i = 0; i < 4; i++) {
    f32x4 mx;
#pragma unroll
    for (int r = 0; r < 4; r++) mx[r] = -1e30f;
#pragma unroll
    for (int j = 0; j <= i; j++)
#pragma unroll
      for (int r = 0; r < 4; r++) {
        float v = sAcc[i][j][r] * 0.125f;
        if (j == i && c > 4 * q + r) v = -1e30f;
        sAcc[i][j][r] = v;
        mx[r] = fmaxf(mx[r], v);
      }
#pragma unroll
    for (int off = 1; off < 16; off <<= 1)
#pragma unroll
      for (int r = 0; r < 4; r++) mx[r] = fmaxf(mx[r], __shfl_xor(mx[r], off));
    f32x4 sm = {};
#pragma unroll
    for (int j = 0; j <= i; j++)
#pragma unroll
      for (int r = 0; r < 4; r++) {
        float e = __expf(sAcc[i][j][r] - mx[r]);
        sm[r] += e;
        Plds[(16 * i + 4 * q + r) * 72 + 16 * j + c] = (f16)e;
      }
#pragma unroll
    for (int off = 1; off < 16; off <<= 1)
#pragma unroll
      for (int r = 0; r < 4; r++) sm[r] += __shfl_xor(sm[r], off);
#pragma unroll
    for (int r = 0; r < 4; r++) invs[i][r] = 1.f / sm[r];
  }
  __syncthreads();

  f32x4 oacc[4][4] = {};
#pragma unroll
  for (int kb = 0; kb < 2; kb++) {
    f16x8 vb[4];
#pragma unroll
    for (int db = 0; db < 4; db++) {
      int d = 16 * db + c;
      vb[db] = *reinterpret_cast<const f16x8*>(&VT[d * 72 + ((32 * kb + 8 * q) ^ (((d >> 3) & 7) << 3))]);
    }
#pragma unroll
    for (int i = 0; i < 4; i++) {
      if (kb == 1 && i < 2) continue;
      f16x8 pa = *reinterpret_cast<const f16x8*>(&Plds[(16 * i + c) * 72 + 32 * kb + 8 * q]);
#pragma unroll
      for (int db = 0; db < 4; db++)
        oacc[i][db] = __builtin_amdgcn_mfma_f32_16x16x32_f16(pa, vb[db], oacc[i][db], 0, 0, 0);
    }
  }

#pragma unroll
  for (int i = 0; i < 4; i++)
#pragma unroll
    for (int db = 0; db < 4; db++)
#pragma unroll
      for (int r = 0; r < 4; r++) {
        int srow = 16 * i + 4 * q + r;
        long tok = (long)(b * 64 + srow) * 16 + p;
        o[tok * EDIM + h * 64 + 16 * db + c] = (f16)(oacc[i][db][r] * invs[i][r]);
      }
}

// ======== LayerNorm over 512 (fp16 in): 4 rows per 256-thr block ========
template <int FINAL>
__global__ __launch_bounds__(256) void k_ln_h(const f16* __restrict__ r,
                                              const float* __restrict__ g,
                                              const float* __restrict__ b,
                                              float* __restrict__ xf,
                                              f16* __restrict__ xh) {
  int row = blockIdx.x * 4 + (threadIdx.x >> 6);
  int lane = threadIdx.x & 63;
  f16x8 v = *reinterpret_cast<const f16x8*>(r + (long)row * EDIM + lane * 8);
  float vals[8];
  float s = 0.f, q = 0.f;
#pragma unroll
  for (int u = 0; u < 8; u++) {
    vals[u] = (float)v[u];
    s += vals[u]; q += vals[u] * vals[u];
  }
#pragma unroll
  for (int off = 32; off; off >>= 1) { s += __shfl_xor(s, off); q += __shfl_xor(q, off); }
  float mean = s * (1.f / EDIM);
  float var = q * (1.f / EDIM) - mean * mean;
  float rs = rsqrtf(var + 1e-5f);
  long base = (long)row * EDIM + lane * 8;
  if (FINAL) {
#pragma unroll
    for (int u = 0; u < 8; u++) {
      int cidx = lane * 8 + u;
      xf[base + u] = (vals[u] - mean) * rs * g[cidx] + b[cidx];
    }
  } else {
    f16x8 y;
#pragma unroll
    for (int u = 0; u < 8; u++) {
      int cidx = lane * 8 + u;
      y[u] = (f16)((vals[u] - mean) * rs * g[cidx] + b[cidx]);
    }
    *reinterpret_cast<f16x8*>(xh + base) = y;
  }
}

// ======== head: pool over patches, pair-concat, LN(1024), @ h_w + h_b ========
__global__ __launch_bounds__(256) void k_head(const float* __restrict__ xf,
                                              const float* __restrict__ g,
                                              const float* __restrict__ b,
                                              const float* __restrict__ hw,
                                              const float* __restrict__ hb,
                                              float* __restrict__ actions) {
  __shared__ float lnv[1024];
  __shared__ float red[10];
  int blk = blockIdx.x;               // 16*63
  int bb = blk / 63, t = blk % 63;
  int tid = threadIdx.x;
  float vals[4];
  float s = 0.f, q = 0.f;
#pragma unroll
  for (int u = 0; u < 4; u++) {
    int idx = tid * 4 + u;            // 0..1023
    int half = idx >> 9, e = idx & 511;
    const float* base = xf + (long)(((bb * 64) + t + half) * 16) * EDIM + e;
    float acc = 0.f;
#pragma unroll
    for (int p = 0; p < 16; p++) acc += base[p * EDIM];
    acc *= (1.f / 16.f);
    vals[u] = acc; s += acc; q += acc * acc;
  }
#pragma unroll
  for (int off = 32; off; off >>= 1) { s += __shfl_xor(s, off); q += __shfl_xor(q, off); }
  if ((tid & 63) == 0) { red[tid >> 6] = s; red[4 + (tid >> 6)] = q; }
  __syncthreads();
  if (tid == 0) {
    float S = red[0] + red[1] + red[2] + red[3];
    float Q = red[4] + red[5] + red[6] + red[7];
    float m = S * (1.f / 1024.f);
    red[8] = m;
    red[9] = rsqrtf(Q * (1.f / 1024.f) - m * m + 1e-5f);
  }
  __syncthreads();
  float m = red[8], rs = red[9];
#pragma unroll
  for (int u = 0; u < 4; u++) {
    int idx = tid * 4 + u;
    lnv[idx] = (vals[u] - m) * rs * g[idx] + b[idx];
  }
  __syncthreads();
  if (tid < 64) {
    float acc = hb[tid];
    for (int e = 0; e < 1024; e++) acc += lnv[e] * hw[e * 64 + tid];
    actions[(long)blk * 64 + tid] = acc;
  }
}

extern "C" void kernel_launch(void* const* d_in, const int* in_sizes, int n_in,
                              void* d_out, int out_size, void* d_ws, size_t ws_size,
                              hipStream_t stream) {
  (void)in_sizes; (void)n_in; (void)out_size; (void)ws_size;
  const float* frames  = (const float*)d_in[0];
  const float* w_patch = (const float*)d_in[1];
  const float* b_patch = (const float*)d_in[2];
  const float* pos     = (const float*)d_in[3];
  const float* s_w[4]  = {(const float*)d_in[4],  (const float*)d_in[5],
                          (const float*)d_in[6],  (const float*)d_in[7]};
  const float* s_bq = (const float*)d_in[8];
  const float* s_bk = (const float*)d_in[9];
  const float* s_bv = (const float*)d_in[10];
  const float* s_bo = (const float*)d_in[11];
  const float* s_lng = (const float*)d_in[12];
  const float* s_lnb = (const float*)d_in[13];
  const float* t_w[4]  = {(const float*)d_in[14], (const float*)d_in[15],
                          (const float*)d_in[16], (const float*)d_in[17]};
  const float* t_bq = (const float*)d_in[18];
  const float* t_bk = (const float*)d_in[19];
  const float* t_bv = (const float*)d_in[20];
  const float* t_bo = (const float*)d_in[21];
  const float* t_lng = (const float*)d_in[22];
  const float* t_lnb = (const float*)d_in[23];
  const float* f_w1 = (const float*)d_in[24];
  const float* f_b1 = (const float*)d_in[25];
  const float* f_w2 = (const float*)d_in[26];
  const float* f_b2 = (const float*)d_in[27];
  const float* f_lng = (const float*)d_in[28];
  const float* f_lnb = (const float*)d_in[29];
  const float* h_lng = (const float*)d_in[30];
  const float* h_lnb = (const float*)d_in[31];
  const float* h_w = (const float*)d_in[32];
  const float* h_b = (const float*)d_in[33];

  char* ws = (char*)d_ws;
  size_t off = 0;
  auto alloc = [&](size_t bytes) { size_t o = off; off += (bytes + 255) & ~(size_t)255; return o; };
  f16* sqkvT = (f16*)(ws + alloc((size_t)6 * 1536 * 512 * 2));
  f16* swoT  = (f16*)(ws + alloc((size_t)6 * 512 * 512 * 2));
  f16* tqkvT = (f16*)(ws + alloc((size_t)6 * 1536 * 512 * 2));
  f16* twoT  = (f16*)(ws + alloc((size_t)6 * 512 * 512 * 2));
  f16* w1T   = (f16*)(ws + alloc((size_t)6 * 2048 * 512 * 2));
  f16* w2T   = (f16*)(ws + alloc((size_t)6 * 512 * 2048 * 2));
  f16* wpT   = (f16*)(ws + alloc((size_t)512 * 768 * 2));
  float* bqkv = (float*)(ws + alloc((size_t)2 * 6 * 1536 * 4));
  f16* xh    = (f16*)(ws + alloc((size_t)NTOK * EDIM * 2));
  char* regC = ws + alloc((size_t)NTOK * 1536 * 2);   // qkv | rbufH (phase-disjoint)
  char* regD = ws + alloc((size_t)NTOK * 2048 * 2);   // P | o | h1 (phase-disjoint)
  f16* qkv   = (f16*)regC;
  f16* rbufH = (f16*)regC;
  f16* Pmat  = (f16*)regD;
  f16* obuf  = (f16*)regD;
  f16* h1    = (f16*)regD;

  dim3 tb(32, 8);
  for (int pre = 0; pre < 2; pre++) {
    const float* const* wsrc = pre ? t_w : s_w;
    f16* qdst = pre ? tqkvT : sqkvT;
    f16* odst = pre ? twoT : swoT;
    for (int wi = 0; wi < 3; wi++)
      k_transpose<<<dim3(16, 16, 6), tb, 0, stream>>>(wsrc[wi], qdst + wi * 512 * 512,
                                                      512, 512, 262144L, 786432L);
    k_transpose<<<dim3(16, 16, 6), tb, 0, stream>>>(wsrc[3], odst, 512, 512, 262144L, 262144L);
  }
  k_transpose<<<dim3(64, 16, 6), tb, 0, stream>>>(f_w1, w1T, 512, 2048, 1048576L, 1048576L);
  k_transpose<<<dim3(16, 64, 6), tb, 0, stream>>>(f_w2, w2T, 2048, 512, 1048576L, 1048576L);
  k_transpose<<<dim3(16, 24, 1), tb, 0, stream>>>(w_patch, wpT, 768, 512, 0L, 0L);
  k_pack_bias<<<72, 256, 0, stream>>>(s_bq, s_bk, s_bv, t_bq, t_bk, t_bv, bqkv);

  k_patchify<<<6144, 256, 0, stream>>>(frames, Pmat);
  // grids: all 1D, count % 8 == 0 (bijective XCD swizzle requirement)
  k_gemm<0, 0, 1><<<512, 256, 0, stream>>>(
      Pmat, wpT, b_patch, nullptr, pos, xh, 512, 768, 4);

  float* out = (float*)d_out;
  float* xf_final = out + 64512;   // second output: x fp32, written by final LN

  for (int l = 0; l < 6; l++) {
    // ---- spatial attention ----
    k_gemm<0, 0, 0><<<1536, 256, 0, stream>>>(
        xh, sqkvT + (size_t)l * 1536 * 512, bqkv + l * 1536,
        nullptr, nullptr, qkv, 1536, 512, 12);
    k_attn_spatial_mfma<<<1024, 256, 0, stream>>>(qkv, obuf);
    k_gemm<0, 1, 0><<<512, 256, 0, stream>>>(
        obuf, swoT + (size_t)l * 512 * 512, s_bo + l * 512,
        xh, nullptr, rbufH, 512, 512, 4);
    k_ln_h<0><<<NTOK / 4, 256, 0, stream>>>(rbufH, s_lng + l * 512, s_lnb + l * 512,
                                            nullptr, xh);
    // ---- temporal attention ----
    k_gemm<0, 0, 0><<<1536, 256, 0, stream>>>(
        xh, tqkvT + (size_t)l * 1536 * 512, bqkv + (6 + l) * 1536,
        nullptr, nullptr, qkv, 1536, 512, 12);
    k_attn_temporal_mfma<<<2048, 64, 0, stream>>>(qkv, obuf);
    k_gemm<0, 1, 0><<<512, 256, 0, stream>>>(
        obuf, twoT + (size_t)l * 512 * 512, t_bo + l * 512,
        xh, nullptr, rbufH, 512, 512, 4);
    k_ln_h<0><<<NTOK / 4, 256, 0, stream>>>(rbufH, t_lng + l * 512, t_lnb + l * 512,
                                            nullptr, xh);
    // ---- FFN ----
    k_gemm_big<1><<<512, 512, 0, stream>>>(
        xh, w1T + (size_t)l * 2048 * 512, f_b1 + l * 2048, h1, 2048, 512, 8);
    k_gemm<0, 1, 0><<<512, 256, 0, stream>>>(
        h1, w2T + (size_t)l * 512 * 2048, f_b2 + l * 512,
        xh, nullptr, rbufH, 512, 2048, 4);
    if (l == 5) {
      k_ln_h<1><<<NTOK / 4, 256, 0, stream>>>(rbufH, f_lng + l * 512, f_lnb + l * 512,
                                              xf_final, nullptr);
    } else {
      k_ln_h<0><<<NTOK / 4, 256, 0, stream>>>(rbufH, f_lng + l * 512, f_lnb + l * 512,
                                              nullptr, xh);
    }
  }

  k_head<<<1008, 256, 0, stream>>>(xf_final, h_lng, h_lnb, h_w, h_b, out);
}

// Round 19
// 1750.632 us; speedup vs baseline: 1.0094x; 1.0032x over previous
//
#include <hip/hip_runtime.h>
#include <hip/hip_bf16.h>

typedef _Float16 f16;
typedef _Float16 f16x8 __attribute__((ext_vector_type(8)));
typedef float f32x4 __attribute__((ext_vector_type(4)));

#define NTOK 16384   // 16*64*16 tokens
#define EDIM 512
#define FFDIM 2048
#define PDIM 768

#define VMCNT(n) asm volatile("s_waitcnt vmcnt(" #n ")")

// async global->LDS DMA, 16B per lane. LDS dest must be linear in lane order.
typedef __attribute__((address_space(3))) unsigned int lds_uint;
typedef __attribute__((address_space(1))) const unsigned int glob_uint;
__device__ __forceinline__ void gl_lds16(const f16* g, f16* l) {
  __builtin_amdgcn_global_load_lds((glob_uint*)g, (lds_uint*)l, 16, 0, 0);
}

// ======== weight transpose: fp32 [B][R][C] -> fp16 [B][C][R] ========
__global__ void k_transpose(const float* __restrict__ src, f16* __restrict__ dst,
                            int R, int C, long srcBS, long dstBS) {
  __shared__ float tile[32][33];
  src += (long)blockIdx.z * srcBS;
  dst += (long)blockIdx.z * dstBS;
  int c0 = blockIdx.x * 32, r0 = blockIdx.y * 32;
  int tx = threadIdx.x, ty = threadIdx.y;
#pragma unroll
  for (int j = ty; j < 32; j += 8)
    tile[j][tx] = src[(long)(r0 + j) * C + (c0 + tx)];
  __syncthreads();
#pragma unroll
  for (int j = ty; j < 32; j += 8)
    dst[(long)(c0 + j) * R + (r0 + tx)] = (f16)tile[tx][j];
}

// ======== pack QKV biases -> [2][6][1536] fp32 ========
__global__ void k_pack_bias(const float* __restrict__ sq, const float* __restrict__ sk,
                            const float* __restrict__ sv, const float* __restrict__ tq,
                            const float* __restrict__ tk, const float* __restrict__ tv,
                            float* __restrict__ dst) {
  int i = blockIdx.x * 256 + threadIdx.x;
  if (i >= 2 * 6 * 1536) return;
  int pre = i / (6 * 1536), rem = i % (6 * 1536), l = rem / 1536, e = rem % 1536;
  const float* s;
  if (pre == 0) s = (e < 512) ? sq : (e < 1024) ? sk : sv;
  else          s = (e < 512) ? tq : (e < 1024) ? tk : tv;
  dst[i] = s[l * 512 + (e & 511)];
}

// ======== patchify: frames fp32 [16][64][3][64][64] -> P fp16 [16384][768] ========
__global__ void k_patchify(const float* __restrict__ frames, f16* __restrict__ P) {
  int gid = blockIdx.x * 256 + threadIdx.x;           // < 16384*96
  int token = gid / 96, chunk = gid % 96;
  int b = token >> 10, s = (token >> 4) & 63, p = token & 15;
  int c = chunk >> 5, rem = chunk & 31, p1 = rem >> 1, p2b = (rem & 1) * 8;
  int h = p >> 2, w = p & 3;
  const float* src = frames + ((long)(((b * 64 + s) * 3 + c) * 64 + h * 16 + p1)) * 64 + w * 16 + p2b;
  float4 f0 = *reinterpret_cast<const float4*>(src);
  float4 f1 = *reinterpret_cast<const float4*>(src + 4);
  f16* dst = P + (long)token * PDIM + chunk * 8;
  dst[0] = (f16)f0.x; dst[1] = (f16)f0.y; dst[2] = (f16)f0.z; dst[3] = (f16)f0.w;
  dst[4] = (f16)f1.x; dst[5] = (f16)f1.y; dst[6] = (f16)f1.z; dst[7] = (f16)f1.w;
}

// ======== MFMA GEMM 128x128 (R11-verified): BK=64 2-deep counted-vmcnt ======
template <int RELU, int RESH, int POS>
__global__ __launch_bounds__(256, 2) void k_gemm(
    const f16* __restrict__ A, const f16* __restrict__ WT,
    const float* __restrict__ bias, const f16* __restrict__ resH,
    const float* __restrict__ pos, f16* __restrict__ outH,
    int N, int K, int nwgx) {
  __shared__ f16 As[2][128 * 64];
  __shared__ f16 Bs[2][128 * 64];
  int tid = threadIdx.x;
  int wave = tid >> 6, lane = tid & 63;
  int wm = wave >> 1, wn = wave & 1;
  int nwg = gridDim.x;
  int id = blockIdx.x;
  int sw = (id & 7) * (nwg >> 3) + (id >> 3);
  int m0 = (sw / nwgx) * 128, n0 = (sw % nwgx) * 128;
  f32x4 acc[4][4] = {};
  int lrow = lane & 15;
  int rs_ = tid >> 3, js = tid & 7;
  int gc = (js ^ (rs_ & 7)) * 8;
  int e = tid * 8;
  int kq = lane >> 4;

  auto STAGE = [&](int buf, int k0) {
#pragma unroll
    for (int q = 0; q < 4; q++)
      gl_lds16(&A [(long)(m0 + q * 32 + rs_) * K + k0 + gc], &As[buf][q * 2048 + e]);
#pragma unroll
    for (int q = 0; q < 4; q++)
      gl_lds16(&WT[(long)(n0 + q * 32 + rs_) * K + k0 + gc], &Bs[buf][q * 2048 + e]);
  };

  int nIter = K >> 6;
  STAGE(0, 0); STAGE(1, 64);
  int cur = 0;
  int kc0 = (kq ^ (lrow & 7)) * 8;
  int kc1 = ((4 + kq) ^ (lrow & 7)) * 8;
  for (int it = 0; it < nIter; ++it) {
    if (it + 1 < nIter) VMCNT(8);
    else               VMCNT(0);
    __builtin_amdgcn_s_barrier();
    f16x8 af[2][4], bfr[2][4];
#pragma unroll
    for (int i = 0; i < 4; i++) {
      af[0][i]  = *reinterpret_cast<const f16x8*>(&As[cur][(wm * 64 + i * 16 + lrow) * 64 + kc0]);
      bfr[0][i] = *reinterpret_cast<const f16x8*>(&Bs[cur][(wn * 64 + i * 16 + lrow) * 64 + kc0]);
    }
    __builtin_amdgcn_sched_barrier(0);
#pragma unroll
    for (int i = 0; i < 4; i++) {
      af[1][i]  = *reinterpret_cast<const f16x8*>(&As[cur][(wm * 64 + i * 16 + lrow) * 64 + kc1]);
      bfr[1][i] = *reinterpret_cast<const f16x8*>(&Bs[cur][(wn * 64 + i * 16 + lrow) * 64 + kc1]);
    }
    asm volatile("s_waitcnt lgkmcnt(8)");
    __builtin_amdgcn_sched_barrier(0);
    __builtin_amdgcn_s_setprio(1);
#pragma unroll
    for (int i = 0; i < 4; i++)
#pragma unroll
      for (int j = 0; j < 4; j++)
        acc[i][j] = __builtin_amdgcn_mfma_f32_16x16x32_f16(af[0][i], bfr[0][j], acc[i][j], 0, 0, 0);
    __builtin_amdgcn_s_setprio(0);
    asm volatile("s_waitcnt lgkmcnt(0)");
    __builtin_amdgcn_sched_barrier(0);
    __builtin_amdgcn_s_barrier();
    if (it + 2 < nIter) STAGE(cur, (it + 2) << 6);
    __builtin_amdgcn_s_setprio(1);
#pragma unroll
    for (int i = 0; i < 4; i++)
#pragma unroll
      for (int j = 0; j < 4; j++)
        acc[i][j] = __builtin_amdgcn_mfma_f32_16x16x32_f16(af[1][i], bfr[1][j], acc[i][j], 0, 0, 0);
    __builtin_amdgcn_s_setprio(0);
    cur ^= 1;
  }
  int rq = lane >> 4;
#pragma unroll
  for (int i = 0; i < 4; i++) {
#pragma unroll
    for (int j = 0; j < 4; j++) {
      int col = n0 + wn * 64 + j * 16 + lrow;
      float bv = bias[col];
#pragma unroll
      for (int rr = 0; rr < 4; rr++) {
        int rowg = m0 + wm * 64 + i * 16 + rq * 4 + rr;
        float v = acc[i][j][rr] + bv;
        if (POS) v += pos[(rowg & 15) * EDIM + col];
        if (RESH) v += (float)resH[(long)rowg * N + col];
        if (RELU) v = fmaxf(v, 0.f);
        outH[(long)rowg * N + col] = (f16)v;
      }
    }
  }
}

// ======== MFMA GEMM 256x256 "big": used for W1 only (grid 512, clean) ======
template <int RELU>
__global__ __launch_bounds__(512, 1) void k_gemm_big(
    const f16* __restrict__ A, const f16* __restrict__ WT,
    const float* __restrict__ bias, f16* __restrict__ outH,
    int N, int K, int nwgx) {
  __shared__ f16 As[2][256 * 64];
  __shared__ f16 Bs[2][256 * 64];
  int tid = threadIdx.x;
  int wave = tid >> 6, lane = tid & 63;
  int wm = wave >> 2, wn = wave & 3;          // 2 x 4 wave grid
  int nwg = gridDim.x;
  int id = blockIdx.x;
  int sw = (id & 7) * (nwg >> 3) + (id >> 3);
  int m0 = (sw / nwgx) * 256, n0 = (sw % nwgx) * 256;
  f32x4 acc[8][4] = {};
  int lrow = lane & 15;
  int rs_ = tid >> 3, js = tid & 7;           // staging row 0..63 / chunk 0..7
  int gc = (js ^ (rs_ & 7)) * 8;
  int e = tid * 8;                            // 0..4095 elem per issue
  int kq = lane >> 4;

  auto STAGE = [&](int buf, int k0) {
#pragma unroll
    for (int q = 0; q < 4; q++)
      gl_lds16(&A [(long)(m0 + q * 64 + rs_) * K + k0 + gc], &As[buf][q * 4096 + e]);
#pragma unroll
    for (int q = 0; q < 4; q++)
      gl_lds16(&WT[(long)(n0 + q * 64 + rs_) * K + k0 + gc], &Bs[buf][q * 4096 + e]);
  };
  auto off = [&](int r, int c) {
    return ((r >> 6) << 12) + ((r & 63) << 6) + (((c ^ (r & 7)) & 7) << 3);
  };

  int nIter = K >> 6;
  STAGE(0, 0); STAGE(1, 64);
  int cur = 0;
  for (int it = 0; it < nIter; ++it) {
    if (it + 1 < nIter) VMCNT(8);
    else               VMCNT(0);
    __builtin_amdgcn_s_barrier();
    f16x8 af[8], bfr[4];
#pragma unroll
    for (int i = 0; i < 8; i++)
      af[i] = *reinterpret_cast<const f16x8*>(&As[cur][off(wm * 128 + i * 16 + lrow, kq)]);
#pragma unroll
    for (int j = 0; j < 4; j++)
      bfr[j] = *reinterpret_cast<const f16x8*>(&Bs[cur][off(wn * 64 + j * 16 + lrow, kq)]);
    asm volatile("s_waitcnt lgkmcnt(0)");
    __builtin_amdgcn_sched_barrier(0);
    __builtin_amdgcn_s_setprio(1);
#pragma unroll
    for (int i = 0; i < 8; i++)
#pragma unroll
      for (int j = 0; j < 4; j++)
        acc[i][j] = __builtin_amdgcn_mfma_f32_16x16x32_f16(af[i], bfr[j], acc[i][j], 0, 0, 0);
    __builtin_amdgcn_s_setprio(0);
#pragma unroll
    for (int i = 0; i < 8; i++)
      af[i] = *reinterpret_cast<const f16x8*>(&As[cur][off(wm * 128 + i * 16 + lrow, 4 + kq)]);
#pragma unroll
    for (int j = 0; j < 4; j++)
      bfr[j] = *reinterpret_cast<const f16x8*>(&Bs[cur][off(wn * 64 + j * 16 + lrow, 4 + kq)]);
    asm volatile("s_waitcnt lgkmcnt(0)");
    __builtin_amdgcn_sched_barrier(0);
    __builtin_amdgcn_s_barrier();              // all reads of buf[cur] done
    if (it + 2 < nIter) STAGE(cur, (it + 2) << 6);
    __builtin_amdgcn_s_setprio(1);
#pragma unroll
    for (int i = 0; i < 8; i++)
#pragma unroll
      for (int j = 0; j < 4; j++)
        acc[i][j] = __builtin_amdgcn_mfma_f32_16x16x32_f16(af[i], bfr[j], acc[i][j], 0, 0, 0);
    __builtin_amdgcn_s_setprio(0);
    cur ^= 1;
  }
  int rq = lane >> 4;
#pragma unroll
  for (int i = 0; i < 8; i++) {
#pragma unroll
    for (int j = 0; j < 4; j++) {
      int col = n0 + wn * 64 + j * 16 + lrow;
      float bv = bias[col];
#pragma unroll
      for (int rr = 0; rr < 4; rr++) {
        int rowg = m0 + wm * 128 + i * 16 + rq * 4 + rr;
        float v = acc[i][j][rr] + bv;
        if (RELU) v = fmaxf(v, 0.f);
        outH[(long)rowg * N + col] = (f16)v;
      }
    }
  }
}

// ======== spatial attention, MFMA: 1 block per frame, 4 waves x 2 heads ======
__global__ __launch_bounds__(256) void k_attn_spatial_mfma(const f16* __restrict__ qkv,
                                                           f16* __restrict__ o) {
  __shared__ f16 PT[4][32][18];     // per-wave P^T scratch, padded stride 18
  int frame = blockIdx.x;           // b*64+s
  int wave = threadIdx.x >> 6, lane = threadIdx.x & 63;
  int c = lane & 15, q = lane >> 4;
  int R0 = frame * 16;
  const f16* qb = qkv + (long)R0 * 1536;

  for (int z = lane; z < 32 * 18; z += 64) (&PT[wave][0][0])[z] = (f16)0.f;
  asm volatile("s_waitcnt lgkmcnt(0)");

#pragma unroll
  for (int hh = 0; hh < 2; hh++) {
    int h = wave * 2 + hh;
    const f16* hb = qb + h * 64;
    f32x4 s = {};
#pragma unroll
    for (int ks = 0; ks < 2; ks++) {
      f16x8 kf = *reinterpret_cast<const f16x8*>(hb + 512 + (long)c * 1536 + ks * 32 + 8 * q);
      f16x8 qf = *reinterpret_cast<const f16x8*>(hb + (long)c * 1536 + ks * 32 + 8 * q);
      s = __builtin_amdgcn_mfma_f32_16x16x32_f16(kf, qf, s, 0, 0, 0);
    }
    float mx = -1e30f;
#pragma unroll
    for (int r = 0; r < 4; r++) { s[r] *= 0.125f; mx = fmaxf(mx, s[r]); }
    mx = fmaxf(mx, __shfl_xor(mx, 16));
    mx = fmaxf(mx, __shfl_xor(mx, 32));
    float e[4], sum = 0.f;
#pragma unroll
    for (int r = 0; r < 4; r++) { e[r] = __expf(s[r] - mx); sum += e[r]; }
    sum += __shfl_xor(sum, 16);
    sum += __shfl_xor(sum, 32);
    float inv = 1.f / sum;
#pragma unroll
    for (int r = 0; r < 4; r++)
      PT[wave][4 * q + r][c] = (f16)(e[r] * inv);
    asm volatile("s_waitcnt lgkmcnt(0)");
    __builtin_amdgcn_sched_barrier(0);
    f16x8 af;
#pragma unroll
    for (int j = 0; j < 8; j++)
      af[j] = PT[wave][8 * q + j][c];   // rows>=16 are zero (K pad)
    asm volatile("s_waitcnt lgkmcnt(0)");
    __builtin_amdgcn_sched_barrier(0);
#pragma unroll
    for (int db = 0; db < 4; db++) {
      f16x8 vb;
#pragma unroll
      for (int j = 0; j < 8; j++) {
        int kp = (8 * q + j) & 15;
        vb[j] = hb[1024 + (long)kp * 1536 + db * 16 + c];
      }
      f32x4 oacc = {};
      oacc = __builtin_amdgcn_mfma_f32_16x16x32_f16(af, vb, oacc, 0, 0, 0);
#pragma unroll
      for (int r = 0; r < 4; r++)
        o[(long)(R0 + 4 * q + r) * EDIM + h * 64 + db * 16 + c] = (f16)oacc[r];
    }
  }
}

// ======== temporal causal attention, MFMA: 1 wave per (b, p, h); S=64, D=64 ====
__global__ __launch_bounds__(64) void k_attn_temporal_mfma(const f16* __restrict__ qkv,
                                                           f16* __restrict__ o) {
  __shared__ f16 Plds[64 * 72];
  __shared__ f16 VT[64 * 72];
  int bp = blockIdx.x >> 3, h = blockIdx.x & 7;
  int b = bp >> 4, p = bp & 15;
  int lane = threadIdx.x;
  int c = lane & 15, q = lane >> 4;
  const long RSTR = 16 * 1536;
  const f16* qb = qkv + ((long)(b * 1024 + p)) * 1536 + h * 64;

  {
    f16x8 z = {};
#pragma unroll
    for (int t = 0; t < 9; t++)
      *reinterpret_cast<f16x8*>(&Plds[(t * 64 + lane) * 8]) = z;
  }
#pragma unroll
  for (int t = 0; t < 8; t++) {
    int s = t * 8 + (lane >> 3), d0 = (lane & 7) * 8;
    f16x8 v = *reinterpret_cast<const f16x8*>(qb + 1024 + (long)s * RSTR + d0);
#pragma unroll
    for (int u = 0; u < 8; u++) {
      int d = d0 + u;
      VT[d * 72 + (s ^ (((d >> 3) & 7) << 3))] = v[u];
    }
  }
  __syncthreads();

  f32x4 sAcc[4][4] = {};
#pragma unroll
  for (int ks = 0; ks < 2; ks++) {
    f16x8 kf[4];
#pragma unroll
    for (int j = 0; j < 4; j++)
      kf[j] = *reinterpret_cast<const f16x8*>(qb + 512 + (long)(16 * j + c) * RSTR + 32 * ks + 8 * q);
#pragma unroll
    for (int i = 0; i < 4; i++) {
      f16x8 qf = *reinterpret_cast<const f16x8*>(qb + (long)(16 * i + c) * RSTR + 32 * ks + 8 * q);
#pragma unroll
      for (int j = 0; j < 4; j++)
        if (j <= i)
          sAcc[i][j] = __builtin_amdgcn_mfma_f32_16x16x32_f16(qf, kf[j], sAcc[i][j], 0, 0, 0);
    }
  }

  f32x4 invs[4];
#pragma unroll
  for (int i = 0; i < 4; i++) {
    f32x4 mx;
#pragma unroll
    for (int r = 0; r < 4; r++) mx[r] = -1e30f;
#pragma unroll
    for (int j = 0; j <= i; j++)
#pragma unroll
      for (int r = 0; r < 4; r++) {
        float v = sAcc[i][j][r] * 0.125f;
        if (j == i && c > 4 * q + r) v = -1e30f;
        sAcc[i][j][r] = v;
        mx[r] = fmaxf(mx[r], v);
      }
#pragma unroll
    for (int off = 1; off < 16; off <<= 1)
#pragma unroll
      for (int r = 0; r < 4; r++) mx[r] = fmaxf(mx[r], __shfl_xor(mx[r], off));
    f32x4 sm = {};
#pragma unroll
    for (int j = 0; j <= i; j++)
#pragma unroll
      for (int r = 0; r < 4; r++) {
        float e = __expf(sAcc[i][j][r] - mx[r]);
        sm[r] += e;
        Plds[(16 * i + 4 * q + r) * 72 + 16 * j + c] = (f16)e;
      }
#pragma unroll
    for (int off = 1; off < 16; off <<= 1)
#pragma unroll
      for (int r = 0; r < 4; r++) sm[r] += __shfl_xor(sm[r], off);
#pragma unroll
    for (int r = 0; r < 4; r++) invs[i][r] = 1.f / sm[r];
  }
  __syncthreads();

  f32x4 oacc[4][4] = {};
#pragma unroll
  for (int kb = 0; kb < 2; kb++) {
    f16x8 vb[4];
#pragma unroll
    for (int db = 0; db < 4; db++) {
      int d = 16 * db + c;
      vb[db] = *reinterpret_cast<const f16x8*>(&VT[d * 72 + ((32 * kb + 8 * q) ^ (((d >> 3) & 7) << 3))]);
    }
#pragma unroll
    for (int i = 0; i < 4; i++) {
      if (kb == 1 && i < 2) continue;
      f16x8 pa = *reinterpret_cast<const f16x8*>(&Plds[(16 * i + c) * 72 + 32 * kb + 8 * q]);
#pragma unroll
      for (int db = 0; db < 4; db++)
        oacc[i][db] = __builtin_amdgcn_mfma_f32_16x16x32_f16(pa, vb[db], oacc[i][db], 0, 0, 0);
    }
  }

#pragma unroll
  for (int i = 0; i < 4; i++)
#pragma unroll
    for (int db = 0; db < 4; db++)
#pragma unroll
      for (int r = 0; r < 4; r++) {
        int srow = 16 * i + 4 * q + r;
        long tok = (long)(b * 64 + srow) * 16 + p;
        o[tok * EDIM + h * 64 + 16 * db + c] = (f16)(oacc[i][db][r] * invs[i][r]);
      }
}

// ======== LayerNorm over 512 (fp16 in): 4 rows per 256-thr block ========
template <int FINAL>
__global__ __launch_bounds__(256) void k_ln_h(const f16* __restrict__ r,
                                              const float* __restrict__ g,
                                              const float* __restrict__ b,
                                              float* __restrict__ xf,
                                              f16* __restrict__ xh) {
  int row = blockIdx.x * 4 + (threadIdx.x >> 6);
  int lane = threadIdx.x & 63;
  f16x8 v = *reinterpret_cast<const f16x8*>(r + (long)row * EDIM + lane * 8);
  float vals[8];
  float s = 0.f, q = 0.f;
#pragma unroll
  for (int u = 0; u < 8; u++) {
    vals[u] = (float)v[u];
    s += vals[u]; q += vals[u] * vals[u];
  }
#pragma unroll
  for (int off = 32; off; off >>= 1) { s += __shfl_xor(s, off); q += __shfl_xor(q, off); }
  float mean = s * (1.f / EDIM);
  float var = q * (1.f / EDIM) - mean * mean;
  float rs = rsqrtf(var + 1e-5f);
  long base = (long)row * EDIM + lane * 8;
  if (FINAL) {
#pragma unroll
    for (int u = 0; u < 8; u++) {
      int cidx = lane * 8 + u;
      xf[base + u] = (vals[u] - mean) * rs * g[cidx] + b[cidx];
    }
  } else {
    f16x8 y;
#pragma unroll
    for (int u = 0; u < 8; u++) {
      int cidx = lane * 8 + u;
      y[u] = (f16)((vals[u] - mean) * rs * g[cidx] + b[cidx]);
    }
    *reinterpret_cast<f16x8*>(xh + base) = y;
  }
}

// ======== head: pool over patches, pair-concat, LN(1024), @ h_w + h_b ========
__global__ __launch_bounds__(256) void k_head(const float* __restrict__ xf,
                                              const float* __restrict__ g,
                                              const float* __restrict__ b,
                                              const float* __restrict__ hw,
                                              const float* __restrict__ hb,
                                              float* __restrict__ actions) {
  __shared__ float lnv[1024];
  __shared__ float red[10];
  int blk = blockIdx.x;               // 16*63
  int bb = blk / 63, t = blk % 63;
  int tid = threadIdx.x;
  float vals[4];
  float s = 0.f, q = 0.f;
#pragma unroll
  for (int u = 0; u < 4; u++) {
    int idx = tid * 4 + u;            // 0..1023
    int half = idx >> 9, e = idx & 511;
    const float* base = xf + (long)(((bb * 64) + t + half) * 16) * EDIM + e;
    float acc = 0.f;
#pragma unroll
    for (int p = 0; p < 16; p++) acc += base[p * EDIM];
    acc *= (1.f / 16.f);
    vals[u] = acc; s += acc; q += acc * acc;
  }
#pragma unroll
  for (int off = 32; off; off >>= 1) { s += __shfl_xor(s, off); q += __shfl_xor(q, off); }
  if ((tid & 63) == 0) { red[tid >> 6] = s; red[4 + (tid >> 6)] = q; }
  __syncthreads();
  if (tid == 0) {
    float S = red[0] + red[1] + red[2] + red[3];
    float Q = red[4] + red[5] + red[6] + red[7];
    float m = S * (1.f / 1024.f);
    red[8] = m;
    red[9] = rsqrtf(Q * (1.f / 1024.f) - m * m + 1e-5f);
  }
  __syncthreads();
  float m = red[8], rs = red[9];
#pragma unroll
  for (int u = 0; u < 4; u++) {
    int idx = tid * 4 + u;
    lnv[idx] = (vals[u] - m) * rs * g[idx] + b[idx];
  }
  __syncthreads();
  if (tid < 64) {
    float acc = hb[tid];
    for (int e = 0; e < 1024; e++) acc += lnv[e] * hw[e * 64 + tid];
    actions[(long)blk * 64 + tid] = acc;
  }
}

extern "C" void kernel_launch(void* const* d_in, const int* in_sizes, int n_in,
                              void* d_out, int out_size, void* d_ws, size_t ws_size,
                              hipStream_t stream) {
  (void)in_sizes; (void)n_in; (void)out_size; (void)ws_size;
  const float* frames  = (const float*)d_in[0];
  const float* w_patch = (const float*)d_in[1];
  const float* b_patch = (const float*)d_in[2];
  const float* pos     = (const float*)d_in[3];
  const float* s_w[4]  = {(const float*)d_in[4],  (const float*)d_in[5],
                          (const float*)d_in[6],  (const float*)d_in[7]};
  const float* s_bq = (const float*)d_in[8];
  const float* s_bk = (const float*)d_in[9];
  const float* s_bv = (const float*)d_in[10];
  const float* s_bo = (const float*)d_in[11];
  const float* s_lng = (const float*)d_in[12];
  const float* s_lnb = (const float*)d_in[13];
  const float* t_w[4]  = {(const float*)d_in[14], (const float*)d_in[15],
                          (const float*)d_in[16], (const float*)d_in[17]};
  const float* t_bq = (const float*)d_in[18];
  const float* t_bk = (const float*)d_in[19];
  const float* t_bv = (const float*)d_in[20];
  const float* t_bo = (const float*)d_in[21];
  const float* t_lng = (const float*)d_in[22];
  const float* t_lnb = (const float*)d_in[23];
  const float* f_w1 = (const float*)d_in[24];
  const float* f_b1 = (const float*)d_in[25];
  const float* f_w2 = (const float*)d_in[26];
  const float* f_b2 = (const float*)d_in[27];
  const float* f_lng = (const float*)d_in[28];
  const float* f_lnb = (const float*)d_in[29];
  const float* h_lng = (const float*)d_in[30];
  const float* h_lnb = (const float*)d_in[31];
  const float* h_w = (const float*)d_in[32];
  const float* h_b = (const float*)d_in[33];

  char* ws = (char*)d_ws;
  size_t off = 0;
  auto alloc = [&](size_t bytes) { size_t o = off; off += (bytes + 255) & ~(size_t)255; return o; };
  f16* sqkvT = (f16*)(ws + alloc((size_t)6 * 1536 * 512 * 2));
  f16* swoT  = (f16*)(ws + alloc((size_t)6 * 512 * 512 * 2));
  f16* tqkvT = (f16*)(ws + alloc((size_t)6 * 1536 * 512 * 2));
  f16* twoT  = (f16*)(ws + alloc((size_t)6 * 512 * 512 * 2));
  f16* w1T   = (f16*)(ws + alloc((size_t)6 * 2048 * 512 * 2));
  f16* w2T   = (f16*)(ws + alloc((size_t)6 * 512 * 2048 * 2));
  f16* wpT   = (f16*)(ws + alloc((size_t)512 * 768 * 2));
  float* bqkv = (float*)(ws + alloc((size_t)2 * 6 * 1536 * 4));
  f16* xh    = (f16*)(ws + alloc((size_t)NTOK * EDIM * 2));
  char* regC = ws + alloc((size_t)NTOK * 1536 * 2);   // qkv | rbufH (phase-disjoint)
  char* regD = ws + alloc((size_t)NTOK * 2048 * 2);   // P | o | h1 (phase-disjoint)
  f16* qkv   = (f16*)regC;
  f16* rbufH = (f16*)regC;
  f16* Pmat  = (f16*)regD;
  f16* obuf  = (f16*)regD;
  f16* h1    = (f16*)regD;

  dim3 tb(32, 8);
  for (int pre = 0; pre < 2; pre++) {
    const float* const* wsrc = pre ? t_w : s_w;
    f16* qdst = pre ? tqkvT : sqkvT;
    f16* odst = pre ? twoT : swoT;
    for (int wi = 0; wi < 3; wi++)
      k_transpose<<<dim3(16, 16, 6), tb, 0, stream>>>(wsrc[wi], qdst + wi * 512 * 512,
                                                      512, 512, 262144L, 786432L);
    k_transpose<<<dim3(16, 16, 6), tb, 0, stream>>>(wsrc[3], odst, 512, 512, 262144L, 262144L);
  }
  k_transpose<<<dim3(64, 16, 6), tb, 0, stream>>>(f_w1, w1T, 512, 2048, 1048576L, 1048576L);
  k_transpose<<<dim3(16, 64, 6), tb, 0, stream>>>(f_w2, w2T, 2048, 512, 1048576L, 1048576L);
  k_transpose<<<dim3(16, 24, 1), tb, 0, stream>>>(w_patch, wpT, 768, 512, 0L, 0L);
  k_pack_bias<<<72, 256, 0, stream>>>(s_bq, s_bk, s_bv, t_bq, t_bk, t_bv, bqkv);

  k_patchify<<<6144, 256, 0, stream>>>(frames, Pmat);
  // grids: all 1D, count % 8 == 0 (bijective XCD swizzle requirement)
  k_gemm<0, 0, 1><<<512, 256, 0, stream>>>(
      Pmat, wpT, b_patch, nullptr, pos, xh, 512, 768, 4);

  float* out = (float*)d_out;
  float* xf_final = out + 64512;   // second output: x fp32, written by final LN

  for (int l = 0; l < 6; l++) {
    // ---- spatial attention ----
    k_gemm<0, 0, 0><<<1536, 256, 0, stream>>>(
        xh, sqkvT + (size_t)l * 1536 * 512, bqkv + l * 1536,
        nullptr, nullptr, qkv, 1536, 512, 12);
    k_attn_spatial_mfma<<<1024, 256, 0, stream>>>(qkv, obuf);
    k_gemm<0, 1, 0><<<512, 256, 0, stream>>>(
        obuf, swoT + (size_t)l * 512 * 512, s_bo + l * 512,
        xh, nullptr, rbufH, 512, 512, 4);
    k_ln_h<0><<<NTOK / 4, 256, 0, stream>>>(rbufH, s_lng + l * 512, s_lnb + l * 512,
                                            nullptr, xh);
    // ---- temporal attention ----
    k_gemm<0, 0, 0><<<1536, 256, 0, stream>>>(
        xh, tqkvT + (size_t)l * 1536 * 512, bqkv + (6 + l) * 1536,
        nullptr, nullptr, qkv, 1536, 512, 12);
    k_attn_temporal_mfma<<<2048, 64, 0, stream>>>(qkv, obuf);
    k_gemm<0, 1, 0><<<512, 256, 0, stream>>>(
        obuf, twoT + (size_t)l * 512 * 512, t_bo + l * 512,
        xh, nullptr, rbufH, 512, 512, 4);
    k_ln_h<0><<<NTOK / 4, 256, 0, stream>>>(rbufH, t_lng + l * 512, t_lnb + l * 512,
                                            nullptr, xh);
    // ---- FFN ----
    k_gemm_big<1><<<512, 512, 0, stream>>>(
        xh, w1T + (size_t)l * 2048 * 512, f_b1 + l * 2048, h1, 2048, 512, 8);
    k_gemm<0, 1, 0><<<512, 256, 0, stream>>>(
        h1, w2T + (size_t)l * 512 * 2048, f_b2 + l * 512,
        xh, nullptr, rbufH, 512, 2048, 4);
    if (l == 5) {
      k_ln_h<1><<<NTOK / 4, 256, 0, stream>>>(rbufH, f_lng + l * 512, f_lnb + l * 512,
                                              xf_final, nullptr);
    } else {
      k_ln_h<0><<<NTOK / 4, 256, 0, stream>>>(rbufH, f_lng + l * 512, f_lnb + l * 512,
                                              nullptr, xh);
    }
  }

  k_head<<<1008, 256, 0, stream>>>(xf_final, h_lng, h_lnb, h_w, h_b, out);
}